// Round 1
// baseline (1488.415 us; speedup 1.0000x reference)
//
#include <hip/hip_runtime.h>
#include <math.h>

#define N_NODES 50000
#define N_EDGES 1600000
#define IN_DIM  128
#define HID     64
static constexpr float EPS = 1e-6f;

__device__ __forceinline__ float wave_sum(float v) {
#pragma unroll
    for (int off = 32; off >= 1; off >>= 1) v += __shfl_xor(v, off, 64);
    return v;
}

// ---- degree / inverse degree ------------------------------------------------
__global__ void degree_kernel(const int* __restrict__ ei, float* __restrict__ deg) {
    int e = blockIdx.x * blockDim.x + threadIdx.x;
    if (e < N_EDGES) atomicAdd(&deg[ei[N_EDGES + e]], 1.0f);
}

__global__ void invdeg_kernel(float* __restrict__ deg) {
    int n = blockIdx.x * blockDim.x + threadIdx.x;
    if (n < N_NODES) deg[n] = 1.0f / fmaxf(deg[n], 1.0f);
}

// ---- dual GEMM: hs = h@wS, hn = h@wN  (weights [K,64] staged in LDS) --------
// one thread per (node, out-col); a wave covers one node's 64 cols, so the
// h-row loads are wave-uniform (L1 broadcast).
template <int K>
__global__ __launch_bounds__(256) void gemm_dual(
    const float* __restrict__ h, const float* __restrict__ wS,
    const float* __restrict__ wN, float* __restrict__ hs,
    float* __restrict__ hn) {
    __shared__ float sS[K * HID];
    __shared__ float sN[K * HID];
    for (int i = threadIdx.x; i < K * HID; i += 256) {
        sS[i] = wS[i];
        sN[i] = wN[i];
    }
    __syncthreads();
    int gid  = blockIdx.x * 256 + threadIdx.x;
    int node = gid >> 6;
    int j    = gid & 63;
    if (node >= N_NODES) return;
    const float* hr = h + (size_t)node * K;
    float aS = 0.f, aN = 0.f;
#pragma unroll 16
    for (int k = 0; k < K; ++k) {
        float a = hr[k];
        aS = fmaf(a, sS[k * HID + j], aS);
        aN = fmaf(a, sN[k * HID + j], aN);
    }
    hs[(size_t)node * HID + j] = aS;
    hn[(size_t)node * HID + j] = aN;
}

// ---- edge scatter-aggregate: agg[dst] += hn[src]  (one wave per edge) -------
__global__ __launch_bounds__(256) void edge_agg(
    const int* __restrict__ ei, const float* __restrict__ hn,
    float* __restrict__ agg) {
    int wid  = (blockIdx.x * 256 + threadIdx.x) >> 6;
    int lane = threadIdx.x & 63;
    if (wid >= N_EDGES) return;
    int s = ei[wid];
    int d = ei[N_EDGES + wid];
    atomicAdd(&agg[(size_t)d * HID + lane], hn[(size_t)s * HID + lane]);
}

// ---- node update: h = normalize(relu(hs + agg*invdeg)) ----------------------
__global__ __launch_bounds__(256) void update_kernel(
    const float* __restrict__ hs, const float* __restrict__ agg,
    const float* __restrict__ invdeg, float* __restrict__ hout) {
    int gid  = blockIdx.x * 256 + threadIdx.x;
    int node = gid >> 6;
    int lane = threadIdx.x & 63;
    if (node >= N_NODES) return;
    size_t idx = (size_t)node * HID + lane;
    float  v   = fmaf(agg[idx], invdeg[node], hs[idx]);
    v          = fmaxf(v, 0.f);
    float ss   = wave_sum(v * v);
    hout[idx]  = v / (sqrtf(ss) + EPS);
}

// ---- MLP head: sigmoid(relu(h@mw1+mb1)@mw2+mb2), one wave per node ----------
__global__ __launch_bounds__(256) void mlp_kernel(
    const float* __restrict__ h, const float* __restrict__ mw1,
    const float* __restrict__ mb1, const float* __restrict__ mw2,
    const float* __restrict__ mb2, float* __restrict__ out) {
    __shared__ float sW1[HID * 32];
    __shared__ float sW2[32];
    for (int i = threadIdx.x; i < HID * 32; i += 256) sW1[i] = mw1[i];
    if (threadIdx.x < 32) sW2[threadIdx.x] = mw2[threadIdx.x];
    __syncthreads();
    int gid  = blockIdx.x * 256 + threadIdx.x;
    int node = gid >> 6;
    int lane = threadIdx.x & 63;
    if (node >= N_NODES) return;
    const float* hr = h + (size_t)node * HID;
    float        p  = 0.f;
    if (lane < 32) {
        float acc = mb1[lane];
#pragma unroll
        for (int k = 0; k < HID; ++k) acc = fmaf(hr[k], sW1[k * 32 + lane], acc);
        p = fmaxf(acc, 0.f) * sW2[lane];
    }
    float s = wave_sum(p);
    if (lane == 0) out[node] = 1.0f / (1.0f + __expf(-(s + mb2[0])));
}

extern "C" void kernel_launch(void* const* d_in, const int* in_sizes, int n_in,
                              void* d_out, int out_size, void* d_ws, size_t ws_size,
                              hipStream_t stream) {
    const float* x   = (const float*)d_in[0];
    const int*   ei  = (const int*)d_in[1];
    const float* w0s = (const float*)d_in[2];
    const float* w0n = (const float*)d_in[3];
    const float* w1s = (const float*)d_in[4];
    const float* w1n = (const float*)d_in[5];
    const float* w2s = (const float*)d_in[6];
    const float* w2n = (const float*)d_in[7];
    const float* mw1 = (const float*)d_in[8];
    const float* mb1 = (const float*)d_in[9];
    const float* mw2 = (const float*)d_in[10];
    const float* mb2 = (const float*)d_in[11];
    float*       out = (float*)d_out;

    const size_t NH = (size_t)N_NODES * HID;  // 3.2e6 floats
    float* ws_f   = (float*)d_ws;
    float* invdeg = ws_f;              // 50k floats (+pad to 50176)
    float* hcur   = ws_f + 50176;
    float* hs     = hcur + NH;
    float* hn     = hs + NH;
    float* agg    = hn + NH;
    // total: 50176 + 4*3.2M floats = ~51.4 MB of d_ws

    const int nodeGrid = (N_NODES * HID) / 256;          // 12500
    const int edgeGrid = (int)(((size_t)N_EDGES * 64) / 256);  // 400000

    // degree -> inv_deg
    hipMemsetAsync(invdeg, 0, N_NODES * sizeof(float), stream);
    degree_kernel<<<(N_EDGES + 255) / 256, 256, 0, stream>>>(ei, invdeg);
    invdeg_kernel<<<(N_NODES + 255) / 256, 256, 0, stream>>>(invdeg);

    // ---- layer 0 (K = 128, input x) ----
    gemm_dual<IN_DIM><<<nodeGrid, 256, 0, stream>>>(x, w0s, w0n, hs, hn);
    hipMemsetAsync(agg, 0, NH * sizeof(float), stream);
    edge_agg<<<edgeGrid, 256, 0, stream>>>(ei, hn, agg);
    update_kernel<<<nodeGrid, 256, 0, stream>>>(hs, agg, invdeg, hcur);

    // ---- layer 1 (K = 64) ----
    gemm_dual<HID><<<nodeGrid, 256, 0, stream>>>(hcur, w1s, w1n, hs, hn);
    hipMemsetAsync(agg, 0, NH * sizeof(float), stream);
    edge_agg<<<edgeGrid, 256, 0, stream>>>(ei, hn, agg);
    update_kernel<<<nodeGrid, 256, 0, stream>>>(hs, agg, invdeg, hcur);

    // ---- layer 2 (K = 64) ----
    gemm_dual<HID><<<nodeGrid, 256, 0, stream>>>(hcur, w2s, w2n, hs, hn);
    hipMemsetAsync(agg, 0, NH * sizeof(float), stream);
    edge_agg<<<edgeGrid, 256, 0, stream>>>(ei, hn, agg);
    update_kernel<<<nodeGrid, 256, 0, stream>>>(hs, agg, invdeg, hcur);

    // ---- MLP head ----
    mlp_kernel<<<nodeGrid, 256, 0, stream>>>(hcur, mw1, mb1, mw2, mb2, out);
}

// Round 2
// 726.323 us; speedup vs baseline: 2.0492x; 2.0492x over previous
//
#include <hip/hip_runtime.h>
#include <math.h>

#define N_NODES 50000
#define N_EDGES 1600000
#define IN_DIM  128
#define HID     64
static constexpr float EPS = 1e-6f;

__device__ __forceinline__ float wave_sum(float v) {
#pragma unroll
    for (int off = 32; off >= 1; off >>= 1) v += __shfl_xor(v, off, 64);
    return v;
}

// ---- degree histogram (int) -------------------------------------------------
__global__ void hist_kernel(const int* __restrict__ ei, int* __restrict__ deg) {
    int e = blockIdx.x * blockDim.x + threadIdx.x;
    if (e < N_EDGES) atomicAdd(&deg[ei[N_EDGES + e]], 1);
}

// ---- exclusive scan over 50k degrees -> rowptr[N+1], cursor[N] --------------
// single workgroup of 1024 threads; wave-shuffle scan + 16 wave partials.
__global__ __launch_bounds__(1024) void scan_kernel(
    const int* __restrict__ deg, int* __restrict__ rowptr,
    int* __restrict__ cursor) {
    __shared__ int parts[16];
    __shared__ int carry;
    int lane = threadIdx.x & 63;
    int wv   = threadIdx.x >> 6;
    if (threadIdx.x == 0) { carry = 0; rowptr[0] = 0; }
    __syncthreads();
    for (int base = 0; base < N_NODES; base += 1024) {
        int i = base + (int)threadIdx.x;
        int v = (i < N_NODES) ? deg[i] : 0;
        int incl = v;
#pragma unroll
        for (int off = 1; off < 64; off <<= 1) {
            int t = __shfl_up(incl, off, 64);
            if (lane >= off) incl += t;
        }
        if (lane == 63) parts[wv] = incl;
        __syncthreads();
        if (threadIdx.x == 0) {
            int run = 0;
#pragma unroll
            for (int w = 0; w < 16; ++w) { int p = parts[w]; parts[w] = run; run += p; }
        }
        __syncthreads();
        int incl_g = carry + parts[wv] + incl;   // inclusive prefix of i
        if (i < N_NODES) {
            rowptr[i + 1] = incl_g;
            cursor[i]     = incl_g - v;          // exclusive prefix = start
        }
        __syncthreads();                          // all carry reads done
        if (threadIdx.x == 1023) carry = carry + parts[15] + incl;
        __syncthreads();
    }
}

// ---- scatter edges into CSR by dst ------------------------------------------
__global__ void scatter_kernel(const int* __restrict__ ei, int* __restrict__ cursor,
                               int* __restrict__ csr_src) {
    int e = blockIdx.x * blockDim.x + threadIdx.x;
    if (e < N_EDGES) {
        int s = ei[e];
        int d = ei[N_EDGES + e];
        int pos = atomicAdd(&cursor[d], 1);
        csr_src[pos] = s;
    }
}

// ---- dual GEMM: hs = h@wS, hn = h@wN  (weights [K,64] staged in LDS) --------
template <int K>
__global__ __launch_bounds__(256) void gemm_dual(
    const float* __restrict__ h, const float* __restrict__ wS,
    const float* __restrict__ wN, float* __restrict__ hs,
    float* __restrict__ hn) {
    __shared__ float sS[K * HID];
    __shared__ float sN[K * HID];
    for (int i = threadIdx.x; i < K * HID; i += 256) {
        sS[i] = wS[i];
        sN[i] = wN[i];
    }
    __syncthreads();
    int gid  = blockIdx.x * 256 + threadIdx.x;
    int node = gid >> 6;
    int j    = gid & 63;
    if (node >= N_NODES) return;
    const float* hr = h + (size_t)node * K;
    float aS = 0.f, aN = 0.f;
#pragma unroll 16
    for (int k = 0; k < K; ++k) {
        float a = hr[k];
        aS = fmaf(a, sS[k * HID + j], aS);
        aN = fmaf(a, sN[k * HID + j], aN);
    }
    hs[(size_t)node * HID + j] = aS;
    hn[(size_t)node * HID + j] = aN;
}

// ---- fused gather-aggregate + update ----------------------------------------
// one wave per node; lane = feature col. No atomics: CSR gather + reg acc.
__global__ __launch_bounds__(256) void agg_update(
    const int* __restrict__ rowptr, const int* __restrict__ csr_src,
    const float* __restrict__ hn, const float* __restrict__ hs,
    float* __restrict__ hout) {
    int node = (blockIdx.x * 256 + threadIdx.x) >> 6;
    int lane = threadIdx.x & 63;
    if (node >= N_NODES) return;
    int beg = rowptr[node];
    int end = rowptr[node + 1];
    float acc = 0.f;
    int e = beg;
    for (; e + 4 <= end; e += 4) {
        int s0 = csr_src[e];
        int s1 = csr_src[e + 1];
        int s2 = csr_src[e + 2];
        int s3 = csr_src[e + 3];
        float v0 = hn[(size_t)s0 * HID + lane];
        float v1 = hn[(size_t)s1 * HID + lane];
        float v2 = hn[(size_t)s2 * HID + lane];
        float v3 = hn[(size_t)s3 * HID + lane];
        acc += (v0 + v1) + (v2 + v3);
    }
    for (; e < end; ++e) acc += hn[(size_t)csr_src[e] * HID + lane];
    float invdeg = 1.0f / fmaxf((float)(end - beg), 1.0f);
    size_t idx = (size_t)node * HID + lane;
    float  v   = fmaf(acc, invdeg, hs[idx]);
    v          = fmaxf(v, 0.f);
    float ss   = wave_sum(v * v);
    hout[idx]  = v / (sqrtf(ss) + EPS);
}

// ---- MLP head: sigmoid(relu(h@mw1+mb1)@mw2+mb2), one wave per node ----------
__global__ __launch_bounds__(256) void mlp_kernel(
    const float* __restrict__ h, const float* __restrict__ mw1,
    const float* __restrict__ mb1, const float* __restrict__ mw2,
    const float* __restrict__ mb2, float* __restrict__ out) {
    __shared__ float sW1[HID * 32];
    __shared__ float sW2[32];
    for (int i = threadIdx.x; i < HID * 32; i += 256) sW1[i] = mw1[i];
    if (threadIdx.x < 32) sW2[threadIdx.x] = mw2[threadIdx.x];
    __syncthreads();
    int gid  = blockIdx.x * 256 + threadIdx.x;
    int node = gid >> 6;
    int lane = threadIdx.x & 63;
    if (node >= N_NODES) return;
    const float* hr = h + (size_t)node * HID;
    float        p  = 0.f;
    if (lane < 32) {
        float acc = mb1[lane];
#pragma unroll
        for (int k = 0; k < HID; ++k) acc = fmaf(hr[k], sW1[k * 32 + lane], acc);
        p = fmaxf(acc, 0.f) * sW2[lane];
    }
    float s = wave_sum(p);
    if (lane == 0) out[node] = 1.0f / (1.0f + __expf(-(s + mb2[0])));
}

extern "C" void kernel_launch(void* const* d_in, const int* in_sizes, int n_in,
                              void* d_out, int out_size, void* d_ws, size_t ws_size,
                              hipStream_t stream) {
    const float* x   = (const float*)d_in[0];
    const int*   ei  = (const int*)d_in[1];
    const float* w0s = (const float*)d_in[2];
    const float* w0n = (const float*)d_in[3];
    const float* w1s = (const float*)d_in[4];
    const float* w1n = (const float*)d_in[5];
    const float* w2s = (const float*)d_in[6];
    const float* w2n = (const float*)d_in[7];
    const float* mw1 = (const float*)d_in[8];
    const float* mb1 = (const float*)d_in[9];
    const float* mw2 = (const float*)d_in[10];
    const float* mb2 = (const float*)d_in[11];
    float*       out = (float*)d_out;

    // ---- workspace layout ----
    int* deg     = (int*)d_ws;            // 50176
    int* cursor  = deg + 50176;           // 50176
    int* rowptr  = cursor + 50176;        // 50001 (pad 50432)
    int* csr_src = rowptr + 50432;        // 1.6M
    float* hcur  = (float*)(csr_src + N_EDGES);
    const size_t NH = (size_t)N_NODES * HID;  // 3.2e6
    float* hs = hcur + NH;
    float* hn = hs + NH;
    // total ~45 MB

    const int nodeGrid = (N_NODES * HID) / 256;  // 12500

    // ---- CSR build ----
    hipMemsetAsync(deg, 0, N_NODES * sizeof(int), stream);
    hist_kernel<<<(N_EDGES + 255) / 256, 256, 0, stream>>>(ei, deg);
    scan_kernel<<<1, 1024, 0, stream>>>(deg, rowptr, cursor);
    scatter_kernel<<<(N_EDGES + 255) / 256, 256, 0, stream>>>(ei, cursor, csr_src);

    // ---- layer 0 (K = 128, input x) ----
    gemm_dual<IN_DIM><<<nodeGrid, 256, 0, stream>>>(x, w0s, w0n, hs, hn);
    agg_update<<<nodeGrid, 256, 0, stream>>>(rowptr, csr_src, hn, hs, hcur);

    // ---- layer 1 ----
    gemm_dual<HID><<<nodeGrid, 256, 0, stream>>>(hcur, w1s, w1n, hs, hn);
    agg_update<<<nodeGrid, 256, 0, stream>>>(rowptr, csr_src, hn, hs, hcur);

    // ---- layer 2 ----
    gemm_dual<HID><<<nodeGrid, 256, 0, stream>>>(hcur, w2s, w2n, hs, hn);
    agg_update<<<nodeGrid, 256, 0, stream>>>(rowptr, csr_src, hn, hs, hcur);

    // ---- MLP head ----
    mlp_kernel<<<nodeGrid, 256, 0, stream>>>(hcur, mw1, mb1, mw2, mb2, out);
}

// Round 3
// 554.960 us; speedup vs baseline: 2.6820x; 1.3088x over previous
//
#include <hip/hip_runtime.h>
#include <hip/hip_bf16.h>
#include <math.h>

#define N_NODES 50000
#define N_EDGES 1600000
#define IN_DIM  128
#define HID     64
static constexpr float EPS = 1e-6f;

typedef __attribute__((ext_vector_type(8))) short   short8;   // 8 bf16 (4 VGPR)
typedef __attribute__((ext_vector_type(4))) float   f32x4;    // MFMA acc

__device__ __forceinline__ float bf2f(unsigned short u) {
    union { unsigned int i; float f; } c; c.i = ((unsigned int)u) << 16; return c.f;
}
__device__ __forceinline__ unsigned short f2bf(float f) {   // round-nearest-even
    union { float f; unsigned int i; } c; c.f = f;
    unsigned int r = c.i + 0x7FFFu + ((c.i >> 16) & 1u);
    return (unsigned short)(r >> 16);
}

__device__ __forceinline__ float wave_sum(float v) {
#pragma unroll
    for (int off = 32; off >= 1; off >>= 1) v += __shfl_xor(v, off, 64);
    return v;
}

// ---- degree histogram (int) -------------------------------------------------
__global__ void hist_kernel(const int* __restrict__ ei, int* __restrict__ deg) {
    int e = blockIdx.x * blockDim.x + threadIdx.x;
    if (e < N_EDGES) atomicAdd(&deg[ei[N_EDGES + e]], 1);
}

// ---- exclusive scan over 50k degrees -> rowptr[N+1], cursor[N] --------------
__global__ __launch_bounds__(1024) void scan_kernel(
    const int* __restrict__ deg, int* __restrict__ rowptr,
    int* __restrict__ cursor) {
    __shared__ int parts[16];
    __shared__ int carry;
    int lane = threadIdx.x & 63;
    int wv   = threadIdx.x >> 6;
    if (threadIdx.x == 0) { carry = 0; rowptr[0] = 0; }
    __syncthreads();
    for (int base = 0; base < N_NODES; base += 1024) {
        int i = base + (int)threadIdx.x;
        int v = (i < N_NODES) ? deg[i] : 0;
        int incl = v;
#pragma unroll
        for (int off = 1; off < 64; off <<= 1) {
            int t = __shfl_up(incl, off, 64);
            if (lane >= off) incl += t;
        }
        if (lane == 63) parts[wv] = incl;
        __syncthreads();
        if (threadIdx.x == 0) {
            int run = 0;
#pragma unroll
            for (int w = 0; w < 16; ++w) { int p = parts[w]; parts[w] = run; run += p; }
        }
        __syncthreads();
        int incl_g = carry + parts[wv] + incl;
        if (i < N_NODES) {
            rowptr[i + 1] = incl_g;
            cursor[i]     = incl_g - v;
        }
        __syncthreads();
        if (threadIdx.x == 1023) carry = carry + parts[15] + incl;
        __syncthreads();
    }
}

// ---- scatter edges into CSR by dst ------------------------------------------
__global__ void scatter_kernel(const int* __restrict__ ei, int* __restrict__ cursor,
                               int* __restrict__ csr_src) {
    int e = blockIdx.x * blockDim.x + threadIdx.x;
    if (e < N_EDGES) {
        int s = ei[e];
        int d = ei[N_EDGES + e];
        int pos = atomicAdd(&cursor[d], 1);
        csr_src[pos] = s;
    }
}

// ---- pack W[K x 64] fp32 -> bf16 MFMA B-fragment order ----------------------
// frag slot = ((c*4 + t)*64 + lane); element j of slot = W[c*32+quad*8+j][t*16+m]
template <int K>
__global__ void pack_weights(const float* __restrict__ wS, const float* __restrict__ wN,
                             unsigned short* __restrict__ pS, unsigned short* __restrict__ pN) {
    constexpr int NSLOT = (K / 32) * 4 * 64;
    int slot = blockIdx.x * blockDim.x + threadIdx.x;
    if (slot >= NSLOT) return;
    int lane = slot & 63;
    int ct   = slot >> 6;
    int t    = ct & 3;
    int c    = ct >> 2;
    int m    = lane & 15;
    int quad = lane >> 4;
    int col  = t * 16 + m;
#pragma unroll
    for (int j = 0; j < 8; ++j) {
        int k = c * 32 + quad * 8 + j;
        pS[slot * 8 + j] = f2bf(wS[k * 64 + col]);
        pN[slot * 8 + j] = f2bf(wN[k * 64 + col]);
    }
}

// ---- fp32 -> bf16 bulk convert (x) ------------------------------------------
__global__ void f32_to_bf16(const float* __restrict__ src, unsigned short* __restrict__ dst,
                            int n4) {
    int i = blockIdx.x * blockDim.x + threadIdx.x;
    if (i >= n4) return;
    f32x4 v = ((const f32x4*)src)[i];
    dst[i * 4 + 0] = f2bf(v[0]);
    dst[i * 4 + 1] = f2bf(v[1]);
    dst[i * 4 + 2] = f2bf(v[2]);
    dst[i * 4 + 3] = f2bf(v[3]);
}

// ---- dual GEMM via MFMA: hs = A@wS (fp32), hn = A@wN (bf16) -----------------
// one wave per 16-node tile; 4 col-tiles x 2 matrices = 8 mfma per 32-K chunk.
template <int K>
__global__ __launch_bounds__(256) void gemm_dual_mfma(
    const unsigned short* __restrict__ A,   // [N_NODES x K] bf16
    const unsigned short* __restrict__ pS,  // packed B frags
    const unsigned short* __restrict__ pN,
    float* __restrict__ hs, unsigned short* __restrict__ hnb) {
    constexpr int NC = K / 32;
    int lane = threadIdx.x & 63;
    int wv   = threadIdx.x >> 6;
    int tile = blockIdx.x * 4 + wv;
    if (tile >= N_NODES / 16) return;
    int m    = lane & 15;
    int quad = lane >> 4;

    const short8* Af  = (const short8*)(A + ((size_t)tile * 16 + m) * K + quad * 8);
    const short8* pSf = (const short8*)pS;
    const short8* pNf = (const short8*)pN;

    f32x4 accS[4], accN[4];
#pragma unroll
    for (int t = 0; t < 4; ++t) {
        accS[t] = (f32x4){0.f, 0.f, 0.f, 0.f};
        accN[t] = (f32x4){0.f, 0.f, 0.f, 0.f};
    }
#pragma unroll
    for (int c = 0; c < NC; ++c) {
        short8 a = Af[c * 4];   // c*32 ushorts = c*4 short8
#pragma unroll
        for (int t = 0; t < 4; ++t) {
            short8 bs = pSf[(c * 4 + t) * 64 + lane];
            short8 bn = pNf[(c * 4 + t) * 64 + lane];
            accS[t] = __builtin_amdgcn_mfma_f32_16x16x32_bf16(a, bs, accS[t], 0, 0, 0);
            accN[t] = __builtin_amdgcn_mfma_f32_16x16x32_bf16(a, bn, accN[t], 0, 0, 0);
        }
    }
    int row0 = tile * 16 + quad * 4;
#pragma unroll
    for (int t = 0; t < 4; ++t) {
#pragma unroll
        for (int r = 0; r < 4; ++r) {
            size_t o = (size_t)(row0 + r) * HID + t * 16 + m;
            hs[o]  = accS[t][r];
            hnb[o] = f2bf(accN[t][r]);
        }
    }
}

// ---- fused gather-aggregate + update (bf16 gather, bf16 h out) --------------
__global__ __launch_bounds__(256) void agg_update(
    const int* __restrict__ rowptr, const int* __restrict__ csr_src,
    const unsigned short* __restrict__ hnb, const float* __restrict__ hs,
    unsigned short* __restrict__ hb_out) {
    int node = (blockIdx.x * 256 + threadIdx.x) >> 6;
    int lane = threadIdx.x & 63;
    if (node >= N_NODES) return;
    int beg = rowptr[node];
    int end = rowptr[node + 1];
    float acc = 0.f;
    int e = beg;
    for (; e + 4 <= end; e += 4) {
        int s0 = csr_src[e];
        int s1 = csr_src[e + 1];
        int s2 = csr_src[e + 2];
        int s3 = csr_src[e + 3];
        float v0 = bf2f(hnb[(size_t)s0 * HID + lane]);
        float v1 = bf2f(hnb[(size_t)s1 * HID + lane]);
        float v2 = bf2f(hnb[(size_t)s2 * HID + lane]);
        float v3 = bf2f(hnb[(size_t)s3 * HID + lane]);
        acc += (v0 + v1) + (v2 + v3);
    }
    for (; e < end; ++e) acc += bf2f(hnb[(size_t)csr_src[e] * HID + lane]);
    float invdeg = 1.0f / fmaxf((float)(end - beg), 1.0f);
    size_t idx = (size_t)node * HID + lane;
    float  v   = fmaf(acc, invdeg, hs[idx]);
    v          = fmaxf(v, 0.f);
    float ss   = wave_sum(v * v);
    hb_out[idx] = f2bf(v / (sqrtf(ss) + EPS));
}

// ---- MLP head: sigmoid(relu(h@mw1+mb1)@mw2+mb2), one wave per node ----------
__global__ __launch_bounds__(256) void mlp_kernel(
    const unsigned short* __restrict__ hb, const float* __restrict__ mw1,
    const float* __restrict__ mb1, const float* __restrict__ mw2,
    const float* __restrict__ mb2, float* __restrict__ out) {
    __shared__ float sW1[HID * 32];
    __shared__ float sW2[32];
    for (int i = threadIdx.x; i < HID * 32; i += 256) sW1[i] = mw1[i];
    if (threadIdx.x < 32) sW2[threadIdx.x] = mw2[threadIdx.x];
    __syncthreads();
    int gid  = blockIdx.x * 256 + threadIdx.x;
    int node = gid >> 6;
    int lane = threadIdx.x & 63;
    if (node >= N_NODES) return;
    const unsigned short* hr = hb + (size_t)node * HID;
    float p = 0.f;
    if (lane < 32) {
        float acc = mb1[lane];
#pragma unroll
        for (int k = 0; k < HID; ++k) acc = fmaf(bf2f(hr[k]), sW1[k * 32 + lane], acc);
        p = fmaxf(acc, 0.f) * sW2[lane];
    }
    float s = wave_sum(p);
    if (lane == 0) out[node] = 1.0f / (1.0f + __expf(-(s + mb2[0])));
}

extern "C" void kernel_launch(void* const* d_in, const int* in_sizes, int n_in,
                              void* d_out, int out_size, void* d_ws, size_t ws_size,
                              hipStream_t stream) {
    const float* x   = (const float*)d_in[0];
    const int*   ei  = (const int*)d_in[1];
    const float* w0s = (const float*)d_in[2];
    const float* w0n = (const float*)d_in[3];
    const float* w1s = (const float*)d_in[4];
    const float* w1n = (const float*)d_in[5];
    const float* w2s = (const float*)d_in[6];
    const float* w2n = (const float*)d_in[7];
    const float* mw1 = (const float*)d_in[8];
    const float* mb1 = (const float*)d_in[9];
    const float* mw2 = (const float*)d_in[10];
    const float* mb2 = (const float*)d_in[11];
    float*       out = (float*)d_out;

    // ---- workspace layout (16B-aligned sections) ----
    int* deg     = (int*)d_ws;                 // 50176
    int* cursor  = deg + 50176;                // 50176
    int* rowptr  = cursor + 50176;             // 50432 (>= N+1)
    int* csr_src = rowptr + 50432;             // 1.6M
    unsigned short* xb  = (unsigned short*)(csr_src + N_EDGES);       // 50000*128
    float*          hs  = (float*)(xb + (size_t)N_NODES * IN_DIM);    // 50000*64 f32
    unsigned short* hnb = (unsigned short*)(hs + (size_t)N_NODES * HID);
    unsigned short* hb  = hnb + (size_t)N_NODES * HID;
    unsigned short* p0S = hb + (size_t)N_NODES * HID;                 // 128*64
    unsigned short* p0N = p0S + IN_DIM * HID;
    unsigned short* p1S = p0N + IN_DIM * HID;                         // 64*64
    unsigned short* p1N = p1S + HID * HID;
    unsigned short* p2S = p1N + HID * HID;
    unsigned short* p2N = p2S + HID * HID;
    // total ~45 MB

    const int nodeGrid = (N_NODES * HID) / 256;        // 12500
    const int gemmGrid = (N_NODES / 16 + 3) / 4;       // 782

    // ---- CSR build ----
    hipMemsetAsync(deg, 0, N_NODES * sizeof(int), stream);
    hist_kernel<<<(N_EDGES + 255) / 256, 256, 0, stream>>>(ei, deg);
    scan_kernel<<<1, 1024, 0, stream>>>(deg, rowptr, cursor);
    scatter_kernel<<<(N_EDGES + 255) / 256, 256, 0, stream>>>(ei, cursor, csr_src);

    // ---- weight packing + x conversion ----
    pack_weights<IN_DIM><<<4, 256, 0, stream>>>(w0s, w0n, p0S, p0N);
    pack_weights<HID><<<2, 256, 0, stream>>>(w1s, w1n, p1S, p1N);
    pack_weights<HID><<<2, 256, 0, stream>>>(w2s, w2n, p2S, p2N);
    f32_to_bf16<<<((N_NODES * IN_DIM / 4) + 255) / 256, 256, 0, stream>>>(
        x, xb, N_NODES * IN_DIM / 4);

    // ---- layer 0 (K = 128) ----
    gemm_dual_mfma<IN_DIM><<<gemmGrid, 256, 0, stream>>>(xb, p0S, p0N, hs, hnb);
    agg_update<<<nodeGrid, 256, 0, stream>>>(rowptr, csr_src, hnb, hs, hb);

    // ---- layer 1 ----
    gemm_dual_mfma<HID><<<gemmGrid, 256, 0, stream>>>(hb, p1S, p1N, hs, hnb);
    agg_update<<<nodeGrid, 256, 0, stream>>>(rowptr, csr_src, hnb, hs, hb);

    // ---- layer 2 ----
    gemm_dual_mfma<HID><<<gemmGrid, 256, 0, stream>>>(hb, p2S, p2N, hs, hnb);
    agg_update<<<nodeGrid, 256, 0, stream>>>(rowptr, csr_src, hnb, hs, hb);

    // ---- MLP head ----
    mlp_kernel<<<nodeGrid, 256, 0, stream>>>(hb, mw1, mb1, mw2, mb2, out);
}

// Round 4
// 401.420 us; speedup vs baseline: 3.7079x; 1.3825x over previous
//
#include <hip/hip_runtime.h>
#include <hip/hip_bf16.h>
#include <math.h>

#define N_NODES 50000
#define N_EDGES 1600000
#define IN_DIM  128
#define HID     64
#define EPB     4096   // edges per sort block
#define NBLK    391    // ceil(N_EDGES / EPB)
#define NB      391    // ceil(N_NODES / 128) buckets of 128 nodes
static constexpr float EPS = 1e-6f;

typedef __attribute__((ext_vector_type(8))) short   short8;   // 8 bf16 (4 VGPR)
typedef __attribute__((ext_vector_type(4))) float   f32x4;    // MFMA acc

__device__ __forceinline__ float bf2f(unsigned short u) {
    union { unsigned int i; float f; } c; c.i = ((unsigned int)u) << 16; return c.f;
}
__device__ __forceinline__ unsigned short f2bf(float f) {   // round-nearest-even
    union { float f; unsigned int i; } c; c.f = f;
    unsigned int r = c.i + 0x7FFFu + ((c.i >> 16) & 1u);
    return (unsigned short)(r >> 16);
}

__device__ __forceinline__ float wave_sum(float v) {
#pragma unroll
    for (int off = 32; off >= 1; off >>= 1) v += __shfl_xor(v, off, 64);
    return v;
}

// ==== CSR build: binned counting sort (no global atomics, local writes) ======

// per-block bucket histogram
__global__ __launch_bounds__(256) void bucket_count(const int* __restrict__ ei,
                                                    int* __restrict__ blockCounts) {
    __shared__ int hist[NB];
    for (int i = threadIdx.x; i < NB; i += 256) hist[i] = 0;
    __syncthreads();
    int base = blockIdx.x * EPB;
    int lim  = min(EPB, N_EDGES - base);
    for (int i = threadIdx.x; i < lim; i += 256)
        atomicAdd(&hist[ei[N_EDGES + base + i] >> 7], 1);
    __syncthreads();
    for (int b = threadIdx.x; b < NB; b += 256)
        blockCounts[blockIdx.x * NB + b] = hist[b];
}

// column scans: blockCounts[i][b] -> global write base for (block i, bucket b)
__global__ __launch_bounds__(512) void bucket_scan(int* __restrict__ blockCounts,
                                                   int* __restrict__ bucketBase) {
    __shared__ int totals[NB];
    int t = threadIdx.x;
    if (t < NB) {
        int s = 0;
        for (int i = 0; i < NBLK; ++i) s += blockCounts[i * NB + t];
        totals[t] = s;
    }
    __syncthreads();
    if (t == 0) {
        int run = 0;
        for (int b = 0; b < NB; ++b) {
            int c = totals[b];
            totals[b]     = run;
            bucketBase[b] = run;
            run += c;
        }
        bucketBase[NB] = run;   // == N_EDGES
    }
    __syncthreads();
    if (t < NB) {
        int run = totals[t];
        for (int i = 0; i < NBLK; ++i) {
            int c = blockCounts[i * NB + t];
            blockCounts[i * NB + t] = run;
            run += c;
        }
    }
}

// scatter edges into bucket-sorted order (runs are contiguous per block+bucket)
__global__ __launch_bounds__(256) void bucket_scatter(const int* __restrict__ ei,
                                                      const int* __restrict__ blockCounts,
                                                      int2* __restrict__ bucketEdges) {
    __shared__ int cur[NB];
    for (int b = threadIdx.x; b < NB; b += 256)
        cur[b] = blockCounts[blockIdx.x * NB + b];
    __syncthreads();
    int base = blockIdx.x * EPB;
    int lim  = min(EPB, N_EDGES - base);
    for (int i = threadIdx.x; i < lim; i += 256) {
        int s = ei[base + i];
        int d = ei[N_EDGES + base + i];
        int pos = atomicAdd(&cur[d >> 7], 1);
        bucketEdges[pos] = make_int2(s, d);
    }
}

// per-node degree from bucket-local LDS counts (no global atomics)
__global__ __launch_bounds__(256) void node_count(const int2* __restrict__ bucketEdges,
                                                  const int* __restrict__ bucketBase,
                                                  int* __restrict__ deg) {
    __shared__ int cnt[128];
    if (threadIdx.x < 128) cnt[threadIdx.x] = 0;
    __syncthreads();
    int beg = bucketBase[blockIdx.x], end = bucketBase[blockIdx.x + 1];
    for (int i = beg + threadIdx.x; i < end; i += 256)
        atomicAdd(&cnt[bucketEdges[i].y & 127], 1);
    __syncthreads();
    int node = blockIdx.x * 128 + threadIdx.x;
    if (threadIdx.x < 128 && node < N_NODES) deg[node] = cnt[threadIdx.x];
}

// ---- exclusive scan over 50k degrees -> rowptr[N+1] -------------------------
__global__ __launch_bounds__(1024) void scan_kernel(
    const int* __restrict__ deg, int* __restrict__ rowptr) {
    __shared__ int parts[16];
    __shared__ int carry;
    int lane = threadIdx.x & 63;
    int wv   = threadIdx.x >> 6;
    if (threadIdx.x == 0) { carry = 0; rowptr[0] = 0; }
    __syncthreads();
    for (int base = 0; base < N_NODES; base += 1024) {
        int i = base + (int)threadIdx.x;
        int v = (i < N_NODES) ? deg[i] : 0;
        int incl = v;
#pragma unroll
        for (int off = 1; off < 64; off <<= 1) {
            int t = __shfl_up(incl, off, 64);
            if (lane >= off) incl += t;
        }
        if (lane == 63) parts[wv] = incl;
        __syncthreads();
        if (threadIdx.x == 0) {
            int run = 0;
#pragma unroll
            for (int w = 0; w < 16; ++w) { int p = parts[w]; parts[w] = run; run += p; }
        }
        __syncthreads();
        int incl_g = carry + parts[wv] + incl;
        if (i < N_NODES) rowptr[i + 1] = incl_g;
        __syncthreads();
        if (threadIdx.x == 1023) carry = carry + parts[15] + incl;
        __syncthreads();
    }
}

// final scatter: writes confined to a ~16KB csr_src window per block
__global__ __launch_bounds__(256) void fine_scatter(const int2* __restrict__ bucketEdges,
                                                    const int* __restrict__ bucketBase,
                                                    const int* __restrict__ rowptr,
                                                    int* __restrict__ csr_src) {
    __shared__ int cur[128];
    int node = blockIdx.x * 128 + threadIdx.x;
    if (threadIdx.x < 128) cur[threadIdx.x] = (node < N_NODES) ? rowptr[node] : 0;
    __syncthreads();
    int beg = bucketBase[blockIdx.x], end = bucketBase[blockIdx.x + 1];
    for (int i = beg + threadIdx.x; i < end; i += 256) {
        int2 e  = bucketEdges[i];
        int pos = atomicAdd(&cur[e.y & 127], 1);
        csr_src[pos] = e.x;
    }
}

// ==== compute kernels ========================================================

// pack W[K x 64] fp32 -> bf16 MFMA B-fragment order
template <int K>
__global__ void pack_weights(const float* __restrict__ wS, const float* __restrict__ wN,
                             unsigned short* __restrict__ pS, unsigned short* __restrict__ pN) {
    constexpr int NSLOT = (K / 32) * 4 * 64;
    int slot = blockIdx.x * blockDim.x + threadIdx.x;
    if (slot >= NSLOT) return;
    int lane = slot & 63;
    int ct   = slot >> 6;
    int t    = ct & 3;
    int c    = ct >> 2;
    int m    = lane & 15;
    int quad = lane >> 4;
    int col  = t * 16 + m;
#pragma unroll
    for (int j = 0; j < 8; ++j) {
        int k = c * 32 + quad * 8 + j;
        pS[slot * 8 + j] = f2bf(wS[k * 64 + col]);
        pN[slot * 8 + j] = f2bf(wN[k * 64 + col]);
    }
}

__global__ void f32_to_bf16(const float* __restrict__ src, unsigned short* __restrict__ dst,
                            int n4) {
    int i = blockIdx.x * blockDim.x + threadIdx.x;
    if (i >= n4) return;
    f32x4 v = ((const f32x4*)src)[i];
    dst[i * 4 + 0] = f2bf(v[0]);
    dst[i * 4 + 1] = f2bf(v[1]);
    dst[i * 4 + 2] = f2bf(v[2]);
    dst[i * 4 + 3] = f2bf(v[3]);
}

// dual GEMM via MFMA: hs = A@wS (fp32 out), hn = A@wN (bf16 out)
template <int K>
__global__ __launch_bounds__(256) void gemm_dual_mfma(
    const unsigned short* __restrict__ A,
    const unsigned short* __restrict__ pS,
    const unsigned short* __restrict__ pN,
    float* __restrict__ hs, unsigned short* __restrict__ hnb) {
    constexpr int NC = K / 32;
    int lane = threadIdx.x & 63;
    int wv   = threadIdx.x >> 6;
    int tile = blockIdx.x * 4 + wv;
    if (tile >= N_NODES / 16) return;
    int m    = lane & 15;
    int quad = lane >> 4;

    const short8* Af  = (const short8*)(A + ((size_t)tile * 16 + m) * K + quad * 8);
    const short8* pSf = (const short8*)pS;
    const short8* pNf = (const short8*)pN;

    f32x4 accS[4], accN[4];
#pragma unroll
    for (int t = 0; t < 4; ++t) {
        accS[t] = (f32x4){0.f, 0.f, 0.f, 0.f};
        accN[t] = (f32x4){0.f, 0.f, 0.f, 0.f};
    }
#pragma unroll
    for (int c = 0; c < NC; ++c) {
        short8 a = Af[c * 4];
#pragma unroll
        for (int t = 0; t < 4; ++t) {
            short8 bs = pSf[(c * 4 + t) * 64 + lane];
            short8 bn = pNf[(c * 4 + t) * 64 + lane];
            accS[t] = __builtin_amdgcn_mfma_f32_16x16x32_bf16(a, bs, accS[t], 0, 0, 0);
            accN[t] = __builtin_amdgcn_mfma_f32_16x16x32_bf16(a, bn, accN[t], 0, 0, 0);
        }
    }
    int row0 = tile * 16 + quad * 4;
#pragma unroll
    for (int t = 0; t < 4; ++t) {
#pragma unroll
        for (int r = 0; r < 4; ++r) {
            size_t o = (size_t)(row0 + r) * HID + t * 16 + m;
            hs[o]  = accS[t][r];
            hnb[o] = f2bf(accN[t][r]);
        }
    }
}

// fused gather-aggregate + update: coalesced index loads + shfl broadcast
__global__ __launch_bounds__(256) void agg_update(
    const int* __restrict__ rowptr, const int* __restrict__ csr_src,
    const unsigned short* __restrict__ hnb, const float* __restrict__ hs,
    unsigned short* __restrict__ hb_out) {
    int node = (blockIdx.x * 256 + threadIdx.x) >> 6;
    int lane = threadIdx.x & 63;
    if (node >= N_NODES) return;
    int beg = rowptr[node];
    int end = rowptr[node + 1];
    float acc = 0.f;
    for (int e = beg; e < end; e += 64) {
        int cnt = min(64, end - e);
        int idx = (lane < cnt) ? csr_src[e + lane] : 0;
        int j = 0;
        for (; j + 4 <= cnt; j += 4) {
            int s0 = __shfl(idx, j, 64);
            int s1 = __shfl(idx, j + 1, 64);
            int s2 = __shfl(idx, j + 2, 64);
            int s3 = __shfl(idx, j + 3, 64);
            float v0 = bf2f(hnb[(size_t)s0 * HID + lane]);
            float v1 = bf2f(hnb[(size_t)s1 * HID + lane]);
            float v2 = bf2f(hnb[(size_t)s2 * HID + lane]);
            float v3 = bf2f(hnb[(size_t)s3 * HID + lane]);
            acc += (v0 + v1) + (v2 + v3);
        }
        for (; j < cnt; ++j) {
            int s = __shfl(idx, j, 64);
            acc += bf2f(hnb[(size_t)s * HID + lane]);
        }
    }
    float invdeg = 1.0f / fmaxf((float)(end - beg), 1.0f);
    size_t idx2 = (size_t)node * HID + lane;
    float  v    = fmaf(acc, invdeg, hs[idx2]);
    v           = fmaxf(v, 0.f);
    float ss    = wave_sum(v * v);
    hb_out[idx2] = f2bf(v / (sqrtf(ss) + EPS));
}

// MLP head
__global__ __launch_bounds__(256) void mlp_kernel(
    const unsigned short* __restrict__ hb, const float* __restrict__ mw1,
    const float* __restrict__ mb1, const float* __restrict__ mw2,
    const float* __restrict__ mb2, float* __restrict__ out) {
    __shared__ float sW1[HID * 32];
    __shared__ float sW2[32];
    for (int i = threadIdx.x; i < HID * 32; i += 256) sW1[i] = mw1[i];
    if (threadIdx.x < 32) sW2[threadIdx.x] = mw2[threadIdx.x];
    __syncthreads();
    int gid  = blockIdx.x * 256 + threadIdx.x;
    int node = gid >> 6;
    int lane = threadIdx.x & 63;
    if (node >= N_NODES) return;
    const unsigned short* hr = hb + (size_t)node * HID;
    float p = 0.f;
    if (lane < 32) {
        float acc = mb1[lane];
#pragma unroll
        for (int k = 0; k < HID; ++k) acc = fmaf(bf2f(hr[k]), sW1[k * 32 + lane], acc);
        p = fmaxf(acc, 0.f) * sW2[lane];
    }
    float s = wave_sum(p);
    if (lane == 0) out[node] = 1.0f / (1.0f + __expf(-(s + mb2[0])));
}

extern "C" void kernel_launch(void* const* d_in, const int* in_sizes, int n_in,
                              void* d_out, int out_size, void* d_ws, size_t ws_size,
                              hipStream_t stream) {
    const float* x   = (const float*)d_in[0];
    const int*   ei  = (const int*)d_in[1];
    const float* w0s = (const float*)d_in[2];
    const float* w0n = (const float*)d_in[3];
    const float* w1s = (const float*)d_in[4];
    const float* w1n = (const float*)d_in[5];
    const float* w2s = (const float*)d_in[6];
    const float* w2n = (const float*)d_in[7];
    const float* mw1 = (const float*)d_in[8];
    const float* mb1 = (const float*)d_in[9];
    const float* mw2 = (const float*)d_in[10];
    const float* mb2 = (const float*)d_in[11];
    float*       out = (float*)d_out;

    // ---- workspace layout ----
    int* deg         = (int*)d_ws;               // 50176
    int* rowptr      = deg + 50176;              // 50432
    int* csr_src     = rowptr + 50432;           // 1.6M
    int* blockCounts = csr_src + N_EDGES;        // NBLK*NB = 152881 (pad 153600)
    int* bucketBase  = blockCounts + 153600;     // 512
    int2* bucketEdges = (int2*)(bucketBase + 512);                    // 1.6M int2 (12.8MB)
    unsigned short* xb = (unsigned short*)bucketEdges;                // ALIAS (dead after fine_scatter)
    const size_t NH = (size_t)N_NODES * HID;
    float*          hs  = (float*)(bucketEdges + N_EDGES);
    unsigned short* hnb = (unsigned short*)(hs + NH);
    unsigned short* hb  = hnb + NH;
    unsigned short* p0S = hb + NH;               // 128*64
    unsigned short* p0N = p0S + IN_DIM * HID;
    unsigned short* p1S = p0N + IN_DIM * HID;    // 64*64
    unsigned short* p1N = p1S + HID * HID;
    unsigned short* p2S = p1N + HID * HID;
    unsigned short* p2N = p2S + HID * HID;
    // total ~46 MB

    const int nodeGrid = (N_NODES * HID) / 256;  // 12500
    const int gemmGrid = (N_NODES / 16 + 3) / 4; // 782

    // ---- CSR build (binned counting sort) ----
    bucket_count<<<NBLK, 256, 0, stream>>>(ei, blockCounts);
    bucket_scan<<<1, 512, 0, stream>>>(blockCounts, bucketBase);
    bucket_scatter<<<NBLK, 256, 0, stream>>>(ei, blockCounts, bucketEdges);
    node_count<<<NB, 256, 0, stream>>>(bucketEdges, bucketBase, deg);
    scan_kernel<<<1, 1024, 0, stream>>>(deg, rowptr);
    fine_scatter<<<NB, 256, 0, stream>>>(bucketEdges, bucketBase, rowptr, csr_src);

    // ---- x conversion (overwrites bucketEdges region) + weight packing ----
    f32_to_bf16<<<((N_NODES * IN_DIM / 4) + 255) / 256, 256, 0, stream>>>(
        x, xb, N_NODES * IN_DIM / 4);
    pack_weights<IN_DIM><<<4, 256, 0, stream>>>(w0s, w0n, p0S, p0N);
    pack_weights<HID><<<2, 256, 0, stream>>>(w1s, w1n, p1S, p1N);
    pack_weights<HID><<<2, 256, 0, stream>>>(w2s, w2n, p2S, p2N);

    // ---- layer 0 (K = 128) ----
    gemm_dual_mfma<IN_DIM><<<gemmGrid, 256, 0, stream>>>(xb, p0S, p0N, hs, hnb);
    agg_update<<<nodeGrid, 256, 0, stream>>>(rowptr, csr_src, hnb, hs, hb);

    // ---- layer 1 ----
    gemm_dual_mfma<HID><<<gemmGrid, 256, 0, stream>>>(hb, p1S, p1N, hs, hnb);
    agg_update<<<nodeGrid, 256, 0, stream>>>(rowptr, csr_src, hnb, hs, hb);

    // ---- layer 2 ----
    gemm_dual_mfma<HID><<<gemmGrid, 256, 0, stream>>>(hb, p2S, p2N, hs, hnb);
    agg_update<<<nodeGrid, 256, 0, stream>>>(rowptr, csr_src, hnb, hs, hb);

    // ---- MLP head ----
    mlp_kernel<<<nodeGrid, 256, 0, stream>>>(hb, mw1, mb1, mw2, mb2, out);
}

// Round 5
// 358.395 us; speedup vs baseline: 4.1530x; 1.1200x over previous
//
#include <hip/hip_runtime.h>
#include <hip/hip_bf16.h>
#include <math.h>

#define N_NODES 50000
#define N_EDGES 1600000
#define IN_DIM  128
#define HID     64
#define EPB     4096   // edges per sort block
#define NBLK    391    // ceil(N_EDGES / EPB)
#define NB      391    // ceil(N_NODES / 128) buckets of 128 nodes
static constexpr float EPS = 1e-6f;

typedef __attribute__((ext_vector_type(8))) short   short8;   // 8 bf16 (4 VGPR)
typedef __attribute__((ext_vector_type(4))) float   f32x4;    // MFMA acc

__device__ __forceinline__ float bf2f(unsigned short u) {
    union { unsigned int i; float f; } c; c.i = ((unsigned int)u) << 16; return c.f;
}
__device__ __forceinline__ unsigned short f2bf(float f) {   // round-nearest-even
    union { float f; unsigned int i; } c; c.f = f;
    unsigned int r = c.i + 0x7FFFu + ((c.i >> 16) & 1u);
    return (unsigned short)(r >> 16);
}

__device__ __forceinline__ float wave_sum(float v) {
#pragma unroll
    for (int off = 32; off >= 1; off >>= 1) v += __shfl_xor(v, off, 64);
    return v;
}

// ==== CSR build: binned counting sort (no global atomics, local writes) ======

// per-block bucket histogram
__global__ __launch_bounds__(256) void bucket_count(const int* __restrict__ ei,
                                                    int* __restrict__ blockCounts) {
    __shared__ int hist[NB];
    for (int i = threadIdx.x; i < NB; i += 256) hist[i] = 0;
    __syncthreads();
    int base = blockIdx.x * EPB;
    int lim  = min(EPB, N_EDGES - base);
    for (int i = threadIdx.x; i < lim; i += 256)
        atomicAdd(&hist[ei[N_EDGES + base + i] >> 7], 1);
    __syncthreads();
    for (int b = threadIdx.x; b < NB; b += 256)
        blockCounts[blockIdx.x * NB + b] = hist[b];
}

// column scans: blockCounts[i][b] -> global write base for (block i, bucket b)
__global__ __launch_bounds__(512) void bucket_scan(int* __restrict__ blockCounts,
                                                   int* __restrict__ bucketBase) {
    __shared__ int totals[NB];
    int t = threadIdx.x;
    if (t < NB) {
        int s = 0;
        for (int i = 0; i < NBLK; ++i) s += blockCounts[i * NB + t];
        totals[t] = s;
    }
    __syncthreads();
    if (t == 0) {
        int run = 0;
        for (int b = 0; b < NB; ++b) {
            int c = totals[b];
            totals[b]     = run;
            bucketBase[b] = run;
            run += c;
        }
        bucketBase[NB] = run;   // == N_EDGES
    }
    __syncthreads();
    if (t < NB) {
        int run = totals[t];
        for (int i = 0; i < NBLK; ++i) {
            int c = blockCounts[i * NB + t];
            blockCounts[i * NB + t] = run;
            run += c;
        }
    }
}

// scatter edges into bucket-sorted order (runs are contiguous per block+bucket)
__global__ __launch_bounds__(256) void bucket_scatter(const int* __restrict__ ei,
                                                      const int* __restrict__ blockCounts,
                                                      int2* __restrict__ bucketEdges) {
    __shared__ int cur[NB];
    for (int b = threadIdx.x; b < NB; b += 256)
        cur[b] = blockCounts[blockIdx.x * NB + b];
    __syncthreads();
    int base = blockIdx.x * EPB;
    int lim  = min(EPB, N_EDGES - base);
    for (int i = threadIdx.x; i < lim; i += 256) {
        int s = ei[base + i];
        int d = ei[N_EDGES + base + i];
        int pos = atomicAdd(&cur[d >> 7], 1);
        bucketEdges[pos] = make_int2(s, d);
    }
}

// per-node degree + in-bucket exclusive scan -> rowptr directly.
// rowptr[node] = bucketBase[b] + excl-prefix of per-node counts within bucket b.
__global__ __launch_bounds__(256) void node_scan(const int2* __restrict__ bucketEdges,
                                                 const int* __restrict__ bucketBase,
                                                 int* __restrict__ rowptr) {
    __shared__ int cnt[128];
    __shared__ int half0;
    if (threadIdx.x < 128) cnt[threadIdx.x] = 0;
    __syncthreads();
    int beg = bucketBase[blockIdx.x], end = bucketBase[blockIdx.x + 1];
    for (int i = beg + threadIdx.x; i < end; i += 256)
        atomicAdd(&cnt[bucketEdges[i].y & 127], 1);
    __syncthreads();
    int tid  = threadIdx.x;
    int lane = tid & 63;
    int v    = (tid < 128) ? cnt[tid] : 0;
    int incl = v;
#pragma unroll
    for (int off = 1; off < 64; off <<= 1) {
        int t = __shfl_up(incl, off, 64);
        if (lane >= off) incl += t;
    }
    if (tid == 63) half0 = incl;   // wave-0 total (nodes 0..63 of bucket)
    __syncthreads();
    int base = bucketBase[blockIdx.x] + ((tid >= 64 && tid < 128) ? half0 : 0);
    int node = blockIdx.x * 128 + tid;
    if (tid < 128 && node < N_NODES) rowptr[node] = base + incl - v;
    if (blockIdx.x == 0 && tid == 128) rowptr[N_NODES] = N_EDGES;
}

// final scatter: writes confined to a ~16KB csr_src window per block
__global__ __launch_bounds__(256) void fine_scatter(const int2* __restrict__ bucketEdges,
                                                    const int* __restrict__ bucketBase,
                                                    const int* __restrict__ rowptr,
                                                    int* __restrict__ csr_src) {
    __shared__ int cur[128];
    int node = blockIdx.x * 128 + threadIdx.x;
    if (threadIdx.x < 128) cur[threadIdx.x] = (node < N_NODES) ? rowptr[node] : 0;
    __syncthreads();
    int beg = bucketBase[blockIdx.x], end = bucketBase[blockIdx.x + 1];
    for (int i = beg + threadIdx.x; i < end; i += 256) {
        int2 e  = bucketEdges[i];
        int pos = atomicAdd(&cur[e.y & 127], 1);
        csr_src[pos] = e.x;
    }
}

// ==== compute kernels ========================================================

// pack W[K x 64] fp32 -> bf16 MFMA B-fragment order
template <int K>
__global__ void pack_weights(const float* __restrict__ wS, const float* __restrict__ wN,
                             unsigned short* __restrict__ pS, unsigned short* __restrict__ pN) {
    constexpr int NSLOT = (K / 32) * 4 * 64;
    int slot = blockIdx.x * blockDim.x + threadIdx.x;
    if (slot >= NSLOT) return;
    int lane = slot & 63;
    int ct   = slot >> 6;
    int t    = ct & 3;
    int c    = ct >> 2;
    int m    = lane & 15;
    int quad = lane >> 4;
    int col  = t * 16 + m;
#pragma unroll
    for (int j = 0; j < 8; ++j) {
        int k = c * 32 + quad * 8 + j;
        pS[slot * 8 + j] = f2bf(wS[k * 64 + col]);
        pN[slot * 8 + j] = f2bf(wN[k * 64 + col]);
    }
}

__global__ void f32_to_bf16(const float* __restrict__ src, unsigned short* __restrict__ dst,
                            int n4) {
    int i = blockIdx.x * blockDim.x + threadIdx.x;
    if (i >= n4) return;
    f32x4 v = ((const f32x4*)src)[i];
    dst[i * 4 + 0] = f2bf(v[0]);
    dst[i * 4 + 1] = f2bf(v[1]);
    dst[i * 4 + 2] = f2bf(v[2]);
    dst[i * 4 + 3] = f2bf(v[3]);
}

// dual GEMM via MFMA: hs = A@wS (fp32 out), hn = A@wN (bf16 out)
template <int K>
__global__ __launch_bounds__(256) void gemm_dual_mfma(
    const unsigned short* __restrict__ A,
    const unsigned short* __restrict__ pS,
    const unsigned short* __restrict__ pN,
    float* __restrict__ hs, unsigned short* __restrict__ hnb) {
    constexpr int NC = K / 32;
    int lane = threadIdx.x & 63;
    int wv   = threadIdx.x >> 6;
    int tile = blockIdx.x * 4 + wv;
    if (tile >= N_NODES / 16) return;
    int m    = lane & 15;
    int quad = lane >> 4;

    const short8* Af  = (const short8*)(A + ((size_t)tile * 16 + m) * K + quad * 8);
    const short8* pSf = (const short8*)pS;
    const short8* pNf = (const short8*)pN;

    f32x4 accS[4], accN[4];
#pragma unroll
    for (int t = 0; t < 4; ++t) {
        accS[t] = (f32x4){0.f, 0.f, 0.f, 0.f};
        accN[t] = (f32x4){0.f, 0.f, 0.f, 0.f};
    }
#pragma unroll
    for (int c = 0; c < NC; ++c) {
        short8 a = Af[c * 4];
#pragma unroll
        for (int t = 0; t < 4; ++t) {
            short8 bs = pSf[(c * 4 + t) * 64 + lane];
            short8 bn = pNf[(c * 4 + t) * 64 + lane];
            accS[t] = __builtin_amdgcn_mfma_f32_16x16x32_bf16(a, bs, accS[t], 0, 0, 0);
            accN[t] = __builtin_amdgcn_mfma_f32_16x16x32_bf16(a, bn, accN[t], 0, 0, 0);
        }
    }
    int row0 = tile * 16 + quad * 4;
#pragma unroll
    for (int t = 0; t < 4; ++t) {
#pragma unroll
        for (int r = 0; r < 4; ++r) {
            size_t o = (size_t)(row0 + r) * HID + t * 16 + m;
            hs[o]  = accS[t][r];
            hnb[o] = f2bf(accN[t][r]);
        }
    }
}

// fused gather-aggregate + update: coalesced index loads + shfl broadcast
__global__ __launch_bounds__(256) void agg_update(
    const int* __restrict__ rowptr, const int* __restrict__ csr_src,
    const unsigned short* __restrict__ hnb, const float* __restrict__ hs,
    unsigned short* __restrict__ hb_out) {
    int node = (blockIdx.x * 256 + threadIdx.x) >> 6;
    int lane = threadIdx.x & 63;
    if (node >= N_NODES) return;
    int beg = rowptr[node];
    int end = rowptr[node + 1];
    float acc = 0.f;
    for (int e = beg; e < end; e += 64) {
        int cnt = min(64, end - e);
        int idx = (lane < cnt) ? csr_src[e + lane] : 0;
        int j = 0;
        for (; j + 4 <= cnt; j += 4) {
            int s0 = __shfl(idx, j, 64);
            int s1 = __shfl(idx, j + 1, 64);
            int s2 = __shfl(idx, j + 2, 64);
            int s3 = __shfl(idx, j + 3, 64);
            float v0 = bf2f(hnb[(size_t)s0 * HID + lane]);
            float v1 = bf2f(hnb[(size_t)s1 * HID + lane]);
            float v2 = bf2f(hnb[(size_t)s2 * HID + lane]);
            float v3 = bf2f(hnb[(size_t)s3 * HID + lane]);
            acc += (v0 + v1) + (v2 + v3);
        }
        for (; j < cnt; ++j) {
            int s = __shfl(idx, j, 64);
            acc += bf2f(hnb[(size_t)s * HID + lane]);
        }
    }
    float invdeg = 1.0f / fmaxf((float)(end - beg), 1.0f);
    size_t idx2 = (size_t)node * HID + lane;
    float  v    = fmaf(acc, invdeg, hs[idx2]);
    v           = fmaxf(v, 0.f);
    float ss    = wave_sum(v * v);
    hb_out[idx2] = f2bf(v / (sqrtf(ss) + EPS));
}

// MLP head
__global__ __launch_bounds__(256) void mlp_kernel(
    const unsigned short* __restrict__ hb, const float* __restrict__ mw1,
    const float* __restrict__ mb1, const float* __restrict__ mw2,
    const float* __restrict__ mb2, float* __restrict__ out) {
    __shared__ float sW1[HID * 32];
    __shared__ float sW2[32];
    for (int i = threadIdx.x; i < HID * 32; i += 256) sW1[i] = mw1[i];
    if (threadIdx.x < 32) sW2[threadIdx.x] = mw2[threadIdx.x];
    __syncthreads();
    int gid  = blockIdx.x * 256 + threadIdx.x;
    int node = gid >> 6;
    int lane = threadIdx.x & 63;
    if (node >= N_NODES) return;
    const unsigned short* hr = hb + (size_t)node * HID;
    float p = 0.f;
    if (lane < 32) {
        float acc = mb1[lane];
#pragma unroll
        for (int k = 0; k < HID; ++k) acc = fmaf(bf2f(hr[k]), sW1[k * 32 + lane], acc);
        p = fmaxf(acc, 0.f) * sW2[lane];
    }
    float s = wave_sum(p);
    if (lane == 0) out[node] = 1.0f / (1.0f + __expf(-(s + mb2[0])));
}

extern "C" void kernel_launch(void* const* d_in, const int* in_sizes, int n_in,
                              void* d_out, int out_size, void* d_ws, size_t ws_size,
                              hipStream_t stream) {
    const float* x   = (const float*)d_in[0];
    const int*   ei  = (const int*)d_in[1];
    const float* w0s = (const float*)d_in[2];
    const float* w0n = (const float*)d_in[3];
    const float* w1s = (const float*)d_in[4];
    const float* w1n = (const float*)d_in[5];
    const float* w2s = (const float*)d_in[6];
    const float* w2n = (const float*)d_in[7];
    const float* mw1 = (const float*)d_in[8];
    const float* mb1 = (const float*)d_in[9];
    const float* mw2 = (const float*)d_in[10];
    const float* mb2 = (const float*)d_in[11];
    float*       out = (float*)d_out;

    // ---- workspace layout ----
    int* rowptr      = (int*)d_ws;               // 50432 (>= N+1)
    int* csr_src     = rowptr + 50432;           // 1.6M
    int* blockCounts = csr_src + N_EDGES;        // NBLK*NB = 152881 (pad 153600)
    int* bucketBase  = blockCounts + 153600;     // 512
    int2* bucketEdges = (int2*)(bucketBase + 512);                    // 1.6M int2 (12.8MB)
    unsigned short* xb = (unsigned short*)bucketEdges;                // ALIAS (dead after fine_scatter)
    const size_t NH = (size_t)N_NODES * HID;
    float*          hs  = (float*)(bucketEdges + N_EDGES);
    unsigned short* hnb = (unsigned short*)(hs + NH);
    unsigned short* hb  = hnb + NH;
    unsigned short* p0S = hb + NH;               // 128*64
    unsigned short* p0N = p0S + IN_DIM * HID;
    unsigned short* p1S = p0N + IN_DIM * HID;    // 64*64
    unsigned short* p1N = p1S + HID * HID;
    unsigned short* p2S = p1N + HID * HID;
    unsigned short* p2N = p2S + HID * HID;
    // total ~46 MB

    const int nodeGrid = (N_NODES * HID) / 256;  // 12500
    const int gemmGrid = (N_NODES / 16 + 3) / 4; // 782

    // ---- CSR build (binned counting sort; no global scan) ----
    bucket_count<<<NBLK, 256, 0, stream>>>(ei, blockCounts);
    bucket_scan<<<1, 512, 0, stream>>>(blockCounts, bucketBase);
    bucket_scatter<<<NBLK, 256, 0, stream>>>(ei, blockCounts, bucketEdges);
    node_scan<<<NB, 256, 0, stream>>>(bucketEdges, bucketBase, rowptr);
    fine_scatter<<<NB, 256, 0, stream>>>(bucketEdges, bucketBase, rowptr, csr_src);

    // ---- x conversion (overwrites bucketEdges region) + weight packing ----
    f32_to_bf16<<<((N_NODES * IN_DIM / 4) + 255) / 256, 256, 0, stream>>>(
        x, xb, N_NODES * IN_DIM / 4);
    pack_weights<IN_DIM><<<4, 256, 0, stream>>>(w0s, w0n, p0S, p0N);
    pack_weights<HID><<<2, 256, 0, stream>>>(w1s, w1n, p1S, p1N);
    pack_weights<HID><<<2, 256, 0, stream>>>(w2s, w2n, p2S, p2N);

    // ---- layer 0 (K = 128) ----
    gemm_dual_mfma<IN_DIM><<<gemmGrid, 256, 0, stream>>>(xb, p0S, p0N, hs, hnb);
    agg_update<<<nodeGrid, 256, 0, stream>>>(rowptr, csr_src, hnb, hs, hb);

    // ---- layer 1 ----
    gemm_dual_mfma<HID><<<gemmGrid, 256, 0, stream>>>(hb, p1S, p1N, hs, hnb);
    agg_update<<<nodeGrid, 256, 0, stream>>>(rowptr, csr_src, hnb, hs, hb);

    // ---- layer 2 ----
    gemm_dual_mfma<HID><<<gemmGrid, 256, 0, stream>>>(hb, p2S, p2N, hs, hnb);
    agg_update<<<nodeGrid, 256, 0, stream>>>(rowptr, csr_src, hnb, hs, hb);

    // ---- MLP head ----
    mlp_kernel<<<nodeGrid, 256, 0, stream>>>(hb, mw1, mb1, mw2, mb2, out);
}

// Round 6
// 325.646 us; speedup vs baseline: 4.5707x; 1.1006x over previous
//
#include <hip/hip_runtime.h>
#include <hip/hip_bf16.h>
#include <math.h>

#define N_NODES 50000
#define N_EDGES 1600000
#define IN_DIM  128
#define HID     64
#define EPB     4096   // edges per sort block
#define NBLK    391    // ceil(N_EDGES / EPB)
#define NB      391    // ceil(N_NODES / 128) buckets of 128 nodes
#define CAP     8192   // LDS staging capacity (edges/bucket; mean 4092, 64 sigma margin)
static constexpr float EPS = 1e-6f;

typedef __attribute__((ext_vector_type(8))) short          short8;   // 8 bf16
typedef __attribute__((ext_vector_type(8))) unsigned short ushort8;
typedef __attribute__((ext_vector_type(4))) float          f32x4;

__device__ __forceinline__ float bf2f(unsigned int hi_bits) {   // bits already in [31:16]
    union { unsigned int i; float f; } c; c.i = hi_bits; return c.f;
}
__device__ __forceinline__ unsigned short f2bf(float f) {   // round-nearest-even
    union { float f; unsigned int i; } c; c.f = f;
    unsigned int r = c.i + 0x7FFFu + ((c.i >> 16) & 1u);
    return (unsigned short)(r >> 16);
}

// ==== CSR build: binned counting sort (packed edges, no global atomics) ======

__global__ __launch_bounds__(256) void bucket_count(const int* __restrict__ ei,
                                                    int* __restrict__ blockCounts) {
    __shared__ int hist[NB];
    for (int i = threadIdx.x; i < NB; i += 256) hist[i] = 0;
    __syncthreads();
    int base = blockIdx.x * EPB;
    int lim  = min(EPB, N_EDGES - base);
    for (int i = threadIdx.x; i < lim; i += 256)
        atomicAdd(&hist[ei[N_EDGES + base + i] >> 7], 1);
    __syncthreads();
    for (int b = threadIdx.x; b < NB; b += 256)
        blockCounts[blockIdx.x * NB + b] = hist[b];
}

__global__ __launch_bounds__(512) void bucket_scan(int* __restrict__ blockCounts,
                                                   int* __restrict__ bucketBase) {
    __shared__ int totals[NB];
    int t = threadIdx.x;
    if (t < NB) {
        int s = 0;
        for (int i = 0; i < NBLK; ++i) s += blockCounts[i * NB + t];
        totals[t] = s;
    }
    __syncthreads();
    if (t == 0) {
        int run = 0;
        for (int b = 0; b < NB; ++b) {
            int c = totals[b];
            totals[b]     = run;
            bucketBase[b] = run;
            run += c;
        }
        bucketBase[NB] = run;   // == N_EDGES
    }
    __syncthreads();
    if (t < NB) {
        int run = totals[t];
        for (int i = 0; i < NBLK; ++i) {
            int c = blockCounts[i * NB + t];
            blockCounts[i * NB + t] = run;
            run += c;
        }
    }
}

// scatter edges into bucket-sorted order, packed (src<<7)|(dst&127)
__global__ __launch_bounds__(256) void bucket_scatter(const int* __restrict__ ei,
                                                      const int* __restrict__ blockCounts,
                                                      unsigned int* __restrict__ bucketPacked) {
    __shared__ int cur[NB];
    for (int b = threadIdx.x; b < NB; b += 256)
        cur[b] = blockCounts[blockIdx.x * NB + b];
    __syncthreads();
    int base = blockIdx.x * EPB;
    int lim  = min(EPB, N_EDGES - base);
    for (int i = threadIdx.x; i < lim; i += 256) {
        int s = ei[base + i];
        int d = ei[N_EDGES + base + i];
        int pos = atomicAdd(&cur[d >> 7], 1);
        bucketPacked[pos] = ((unsigned int)s << 7) | (unsigned int)(d & 127);
    }
}

// fused: per-bucket degree count -> in-bucket scan -> rowptr -> local scatter.
// Stages the bucket's packed edges in LDS so the global read happens once.
__global__ __launch_bounds__(256) void node_scan_scatter(
    const unsigned int* __restrict__ bucketPacked, const int* __restrict__ bucketBase,
    int* __restrict__ rowptr, int* __restrict__ csr_src) {
    __shared__ int cnt[128];
    __shared__ int half0;
    __shared__ unsigned int stage[CAP];
    int tid = threadIdx.x;
    if (tid < 128) cnt[tid] = 0;
    __syncthreads();
    int beg = bucketBase[blockIdx.x], end = bucketBase[blockIdx.x + 1];
    int n = end - beg;
    for (int i = tid; i < n; i += 256) {
        unsigned int e = bucketPacked[beg + i];
        if (i < CAP) stage[i] = e;
        atomicAdd(&cnt[e & 127], 1);
    }
    __syncthreads();
    int lane = tid & 63;
    int v    = (tid < 128) ? cnt[tid] : 0;
    int incl = v;
#pragma unroll
    for (int off = 1; off < 64; off <<= 1) {
        int t = __shfl_up(incl, off, 64);
        if (lane >= off) incl += t;
    }
    if (tid == 63) half0 = incl;
    __syncthreads();
    int base  = beg + ((tid >= 64 && tid < 128) ? half0 : 0);
    int start = base + incl - v;
    int node  = blockIdx.x * 128 + tid;
    if (tid < 128) {
        if (node < N_NODES) rowptr[node] = start;
        cnt[tid] = start;   // becomes the scatter cursor
    }
    if (blockIdx.x == 0 && tid == 128) rowptr[N_NODES] = N_EDGES;
    __syncthreads();
    for (int i = tid; i < n; i += 256) {
        unsigned int e = (i < CAP) ? stage[i] : bucketPacked[beg + i];
        int pos = atomicAdd(&cnt[e & 127], 1);
        csr_src[pos] = (int)(e >> 7);
    }
}

// ==== compute kernels ========================================================

// pack W[K x 64] fp32 -> bf16 MFMA B-fragment order
template <int K>
__global__ void pack_weights(const float* __restrict__ wS, const float* __restrict__ wN,
                             unsigned short* __restrict__ pS, unsigned short* __restrict__ pN) {
    constexpr int NSLOT = (K / 32) * 4 * 64;
    int slot = blockIdx.x * blockDim.x + threadIdx.x;
    if (slot >= NSLOT) return;
    int lane = slot & 63;
    int ct   = slot >> 6;
    int t    = ct & 3;
    int c    = ct >> 2;
    int m    = lane & 15;
    int quad = lane >> 4;
    int col  = t * 16 + m;
#pragma unroll
    for (int j = 0; j < 8; ++j) {
        int k = c * 32 + quad * 8 + j;
        pS[slot * 8 + j] = f2bf(wS[k * 64 + col]);
        pN[slot * 8 + j] = f2bf(wN[k * 64 + col]);
    }
}

// dual GEMM via MFMA: hs = A@wS (fp32 out), hn = A@wN (bf16 out).
// F32IN: A is fp32 (layer 0) — convert fragments in registers, no staging pass.
template <int K, bool F32IN>
__global__ __launch_bounds__(256) void gemm_dual_mfma(
    const void* __restrict__ Av,
    const unsigned short* __restrict__ pS,
    const unsigned short* __restrict__ pN,
    float* __restrict__ hs, unsigned short* __restrict__ hnb) {
    constexpr int NC = K / 32;
    int lane = threadIdx.x & 63;
    int wv   = threadIdx.x >> 6;
    int tile = blockIdx.x * 4 + wv;
    if (tile >= N_NODES / 16) return;
    int m    = lane & 15;
    int quad = lane >> 4;

    const short8* pSf = (const short8*)pS;
    const short8* pNf = (const short8*)pN;

    f32x4 accS[4], accN[4];
#pragma unroll
    for (int t = 0; t < 4; ++t) {
        accS[t] = (f32x4){0.f, 0.f, 0.f, 0.f};
        accN[t] = (f32x4){0.f, 0.f, 0.f, 0.f};
    }
#pragma unroll
    for (int c = 0; c < NC; ++c) {
        short8 a;
        if constexpr (F32IN) {
            const float* Af = (const float*)Av + ((size_t)tile * 16 + m) * K + quad * 8 + c * 32;
            f32x4 a0 = *(const f32x4*)Af;
            f32x4 a1 = *(const f32x4*)(Af + 4);
#pragma unroll
            for (int k = 0; k < 4; ++k) a[k]     = (short)f2bf(a0[k]);
#pragma unroll
            for (int k = 0; k < 4; ++k) a[k + 4] = (short)f2bf(a1[k]);
        } else {
            const short8* Af = (const short8*)((const unsigned short*)Av +
                               ((size_t)tile * 16 + m) * K + quad * 8);
            a = Af[c * 4];
        }
#pragma unroll
        for (int t = 0; t < 4; ++t) {
            short8 bs = pSf[(c * 4 + t) * 64 + lane];
            short8 bn = pNf[(c * 4 + t) * 64 + lane];
            accS[t] = __builtin_amdgcn_mfma_f32_16x16x32_bf16(a, bs, accS[t], 0, 0, 0);
            accN[t] = __builtin_amdgcn_mfma_f32_16x16x32_bf16(a, bn, accN[t], 0, 0, 0);
        }
    }
    int row0 = tile * 16 + quad * 4;
#pragma unroll
    for (int t = 0; t < 4; ++t) {
#pragma unroll
        for (int r = 0; r < 4; ++r) {
            size_t o = (size_t)(row0 + r) * HID + t * 16 + m;
            hs[o]  = accS[t][r];
            hnb[o] = f2bf(accN[t][r]);
        }
    }
}

// fused gather-aggregate + update. Lane = (g,r): g = edge slot (8 edges in
// flight), r = 16B chunk of the 128B bf16 row. 8x fewer VMEM instrs than
// one-lane-per-feature.
__global__ __launch_bounds__(256) void agg_update(
    const int* __restrict__ rowptr, const int* __restrict__ csr_src,
    const unsigned short* __restrict__ hnb, const float* __restrict__ hs,
    unsigned short* __restrict__ hb_out) {
    int node = (blockIdx.x * 256 + threadIdx.x) >> 6;
    int lane = threadIdx.x & 63;
    if (node >= N_NODES) return;
    int g = lane >> 3;   // edge slot 0..7
    int r = lane & 7;    // 16B chunk 0..7
    int beg = rowptr[node];
    int end = rowptr[node + 1];
    float acc[8] = {0.f, 0.f, 0.f, 0.f, 0.f, 0.f, 0.f, 0.f};
    for (int e = beg; e < end; e += 64) {
        int cnt = min(64, end - e);
        int idx = (lane < cnt) ? csr_src[e + lane] : 0;
        for (int j = 0; j < cnt; j += 8) {
            int s = __shfl(idx, j + g, 64);
            if (j + g < cnt) {
                uint4 w = *(const uint4*)(hnb + (size_t)s * HID + r * 8);
                acc[0] += bf2f(w.x << 16);  acc[1] += bf2f(w.x & 0xffff0000u);
                acc[2] += bf2f(w.y << 16);  acc[3] += bf2f(w.y & 0xffff0000u);
                acc[4] += bf2f(w.z << 16);  acc[5] += bf2f(w.z & 0xffff0000u);
                acc[6] += bf2f(w.w << 16);  acc[7] += bf2f(w.w & 0xffff0000u);
            }
        }
    }
    // reduce across g (masks 8,16,32): every lane ends with the full sum for its r
#pragma unroll
    for (int k = 0; k < 8; ++k) {
        acc[k] += __shfl_xor(acc[k], 8, 64);
        acc[k] += __shfl_xor(acc[k], 16, 64);
        acc[k] += __shfl_xor(acc[k], 32, 64);
    }
    float invdeg = 1.0f / fmaxf((float)(end - beg), 1.0f);
    const float* hsr = hs + (size_t)node * HID + r * 8;
    f32x4 h0 = *(const f32x4*)hsr;
    f32x4 h1 = *(const f32x4*)(hsr + 4);
    float v[8], ss = 0.f;
#pragma unroll
    for (int k = 0; k < 8; ++k) {
        float hk = (k < 4) ? h0[k] : h1[k - 4];
        v[k] = fmaxf(fmaf(acc[k], invdeg, hk), 0.f);
        ss += v[k] * v[k];
    }
    // reduce across r (masks 1,2,4): g-duplicates identical, so this sums 64 features
    ss += __shfl_xor(ss, 1, 64);
    ss += __shfl_xor(ss, 2, 64);
    ss += __shfl_xor(ss, 4, 64);
    float rs = 1.0f / (sqrtf(ss) + EPS);
    if (lane < 8) {   // g==0 lanes write: 8 lanes x 16B = full 128B row
        ushort8 o;
#pragma unroll
        for (int k = 0; k < 8; ++k) o[k] = f2bf(v[k] * rs);
        *(ushort8*)(hb_out + (size_t)node * HID + r * 8) = o;
    }
}

// MLP head
__global__ __launch_bounds__(256) void mlp_kernel(
    const unsigned short* __restrict__ hb, const float* __restrict__ mw1,
    const float* __restrict__ mb1, const float* __restrict__ mw2,
    const float* __restrict__ mb2, float* __restrict__ out) {
    __shared__ float sW1[HID * 32];
    __shared__ float sW2[32];
    for (int i = threadIdx.x; i < HID * 32; i += 256) sW1[i] = mw1[i];
    if (threadIdx.x < 32) sW2[threadIdx.x] = mw2[threadIdx.x];
    __syncthreads();
    int gid  = blockIdx.x * 256 + threadIdx.x;
    int node = gid >> 6;
    int lane = threadIdx.x & 63;
    if (node >= N_NODES) return;
    const unsigned short* hr = hb + (size_t)node * HID;
    float p = 0.f;
    if (lane < 32) {
        float acc = mb1[lane];
#pragma unroll
        for (int k = 0; k < HID; ++k)
            acc = fmaf(bf2f(((unsigned int)hr[k]) << 16), sW1[k * 32 + lane], acc);
        p = fmaxf(acc, 0.f) * sW2[lane];
    }
    float s = p;
#pragma unroll
    for (int off = 32; off >= 1; off >>= 1) s += __shfl_xor(s, off, 64);
    if (lane == 0) out[node] = 1.0f / (1.0f + __expf(-(s + mb2[0])));
}

extern "C" void kernel_launch(void* const* d_in, const int* in_sizes, int n_in,
                              void* d_out, int out_size, void* d_ws, size_t ws_size,
                              hipStream_t stream) {
    const float* x   = (const float*)d_in[0];
    const int*   ei  = (const int*)d_in[1];
    const float* w0s = (const float*)d_in[2];
    const float* w0n = (const float*)d_in[3];
    const float* w1s = (const float*)d_in[4];
    const float* w1n = (const float*)d_in[5];
    const float* w2s = (const float*)d_in[6];
    const float* w2n = (const float*)d_in[7];
    const float* mw1 = (const float*)d_in[8];
    const float* mb1 = (const float*)d_in[9];
    const float* mw2 = (const float*)d_in[10];
    const float* mb2 = (const float*)d_in[11];
    float*       out = (float*)d_out;

    // ---- workspace layout ----
    int* rowptr      = (int*)d_ws;               // 50432 (>= N+1)
    int* csr_src     = rowptr + 50432;           // 1.6M
    int* blockCounts = csr_src + N_EDGES;        // NBLK*NB = 152881 (pad 153600)
    int* bucketBase  = blockCounts + 153600;     // 512
    unsigned int* bucketPacked = (unsigned int*)(bucketBase + 512);   // 1.6M uint (6.4MB)
    const size_t NH = (size_t)N_NODES * HID;
    float*          hs  = (float*)(bucketPacked + N_EDGES);
    unsigned short* hnb = (unsigned short*)(hs + NH);
    unsigned short* hb  = hnb + NH;
    unsigned short* p0S = hb + NH;               // 128*64
    unsigned short* p0N = p0S + IN_DIM * HID;
    unsigned short* p1S = p0N + IN_DIM * HID;    // 64*64
    unsigned short* p1N = p1S + HID * HID;
    unsigned short* p2S = p1N + HID * HID;
    unsigned short* p2N = p2S + HID * HID;
    // total ~40 MB

    const int nodeGrid = (N_NODES * HID) / 256;  // 12500
    const int gemmGrid = (N_NODES / 16 + 3) / 4; // 782

    // ---- CSR build (binned counting sort; packed; fused scan+scatter) ----
    bucket_count<<<NBLK, 256, 0, stream>>>(ei, blockCounts);
    bucket_scan<<<1, 512, 0, stream>>>(blockCounts, bucketBase);
    bucket_scatter<<<NBLK, 256, 0, stream>>>(ei, blockCounts, bucketPacked);
    node_scan_scatter<<<NB, 256, 0, stream>>>(bucketPacked, bucketBase, rowptr, csr_src);

    // ---- weight packing ----
    pack_weights<IN_DIM><<<4, 256, 0, stream>>>(w0s, w0n, p0S, p0N);
    pack_weights<HID><<<2, 256, 0, stream>>>(w1s, w1n, p1S, p1N);
    pack_weights<HID><<<2, 256, 0, stream>>>(w2s, w2n, p2S, p2N);

    // ---- layer 0 (K = 128, fp32 input converted in-register) ----
    gemm_dual_mfma<IN_DIM, true><<<gemmGrid, 256, 0, stream>>>(x, p0S, p0N, hs, hnb);
    agg_update<<<nodeGrid, 256, 0, stream>>>(rowptr, csr_src, hnb, hs, hb);

    // ---- layer 1 ----
    gemm_dual_mfma<HID, false><<<gemmGrid, 256, 0, stream>>>(hb, p1S, p1N, hs, hnb);
    agg_update<<<nodeGrid, 256, 0, stream>>>(rowptr, csr_src, hnb, hs, hb);

    // ---- layer 2 ----
    gemm_dual_mfma<HID, false><<<gemmGrid, 256, 0, stream>>>(hb, p2S, p2N, hs, hnb);
    agg_update<<<nodeGrid, 256, 0, stream>>>(rowptr, csr_src, hnb, hs, hb);

    // ---- MLP head ----
    mlp_kernel<<<nodeGrid, 256, 0, stream>>>(hb, mw1, mb1, mw2, mb2, out);
}

// Round 7
// 295.056 us; speedup vs baseline: 5.0445x; 1.1037x over previous
//
#include <hip/hip_runtime.h>
#include <hip/hip_bf16.h>
#include <math.h>

#define N_NODES 50000
#define N_EDGES 1600000
#define IN_DIM  128
#define HID     64
#define EPB     4096   // edges per sort block
#define NBLK    391    // ceil(N_EDGES / EPB)
#define NB      391    // ceil(N_NODES / 128) buckets of 128 nodes
#define CAP     8192   // LDS staging capacity (edges/bucket; mean 4092)
static constexpr float EPS = 1e-6f;

typedef __attribute__((ext_vector_type(8))) short          short8;   // 8 bf16
typedef __attribute__((ext_vector_type(8))) unsigned short ushort8;
typedef __attribute__((ext_vector_type(4))) float          f32x4;

__device__ __forceinline__ float bf2f(unsigned int hi_bits) {   // bits already in [31:16]
    union { unsigned int i; float f; } c; c.i = hi_bits; return c.f;
}
__device__ __forceinline__ unsigned short f2bf(float f) {   // round-nearest-even
    union { float f; unsigned int i; } c; c.f = f;
    unsigned int r = c.i + 0x7FFFu + ((c.i >> 16) & 1u);
    return (unsigned short)(r >> 16);
}

// ==== CSR build: binned counting sort (packed edges, no global atomics) ======

__global__ __launch_bounds__(256) void bucket_count(const int* __restrict__ ei,
                                                    int* __restrict__ blockCounts) {
    __shared__ int hist[NB];
    for (int i = threadIdx.x; i < NB; i += 256) hist[i] = 0;
    __syncthreads();
    int base = blockIdx.x * EPB;
    int lim  = min(EPB, N_EDGES - base);
    for (int i = threadIdx.x; i < lim; i += 256)
        atomicAdd(&hist[ei[N_EDGES + base + i] >> 7], 1);
    __syncthreads();
    for (int b = threadIdx.x; b < NB; b += 256)
        blockCounts[blockIdx.x * NB + b] = hist[b];
}

// --- parallel replacement for the old single-block bucket_scan ---------------

// totals[b] = sum_i blockCounts[i][b]   (391 blocks, one column each)
__global__ __launch_bounds__(256) void col_sum(const int* __restrict__ blockCounts,
                                               int* __restrict__ totals) {
    __shared__ int ws[4];
    int b = blockIdx.x;
    int s = 0;
    for (int i = threadIdx.x; i < NBLK; i += 256) s += blockCounts[i * NB + b];
#pragma unroll
    for (int off = 32; off >= 1; off >>= 1) s += __shfl_xor(s, off, 64);
    if ((threadIdx.x & 63) == 0) ws[threadIdx.x >> 6] = s;
    __syncthreads();
    if (threadIdx.x == 0) totals[b] = ws[0] + ws[1] + ws[2] + ws[3];
}

// exclusive scan of totals[0..NB) -> bucketBase[0..NB]   (one wave)
__global__ __launch_bounds__(64) void base_scan(const int* __restrict__ totals,
                                                int* __restrict__ bucketBase) {
    int lane  = threadIdx.x;
    int carry = 0;
    for (int base = 0; base < NB; base += 64) {
        int i = base + lane;
        int v = (i < NB) ? totals[i] : 0;
        int incl = v;
#pragma unroll
        for (int off = 1; off < 64; off <<= 1) {
            int t = __shfl_up(incl, off, 64);
            if (lane >= off) incl += t;
        }
        if (i < NB) bucketBase[i] = carry + incl - v;
        carry += __shfl(incl, 63, 64);
    }
    if (lane == 0) bucketBase[NB] = carry;   // == N_EDGES
}

// blockCounts[i][b] = bucketBase[b] + excl-prefix_i of column b  (391 blocks)
__global__ __launch_bounds__(256) void col_fix(int* __restrict__ blockCounts,
                                               const int* __restrict__ bucketBase) {
    __shared__ int vals[NBLK];
    int b = blockIdx.x;
    for (int i = threadIdx.x; i < NBLK; i += 256) vals[i] = blockCounts[i * NB + b];
    __syncthreads();
    if (threadIdx.x < 64) {
        int lane  = threadIdx.x;
        int carry = bucketBase[b];
        for (int base = 0; base < NBLK; base += 64) {
            int i = base + lane;
            int v = (i < NBLK) ? vals[i] : 0;
            int incl = v;
#pragma unroll
            for (int off = 1; off < 64; off <<= 1) {
                int t = __shfl_up(incl, off, 64);
                if (lane >= off) incl += t;
            }
            if (i < NBLK) vals[i] = carry + incl - v;
            carry += __shfl(incl, 63, 64);
        }
    }
    __syncthreads();
    for (int i = threadIdx.x; i < NBLK; i += 256) blockCounts[i * NB + b] = vals[i];
}

// scatter edges into bucket-sorted order, packed (src<<7)|(dst&127)
__global__ __launch_bounds__(256) void bucket_scatter(const int* __restrict__ ei,
                                                      const int* __restrict__ blockCounts,
                                                      unsigned int* __restrict__ bucketPacked) {
    __shared__ int cur[NB];
    for (int b = threadIdx.x; b < NB; b += 256)
        cur[b] = blockCounts[blockIdx.x * NB + b];
    __syncthreads();
    int base = blockIdx.x * EPB;
    int lim  = min(EPB, N_EDGES - base);
    for (int i = threadIdx.x; i < lim; i += 256) {
        int s = ei[base + i];
        int d = ei[N_EDGES + base + i];
        int pos = atomicAdd(&cur[d >> 7], 1);
        bucketPacked[pos] = ((unsigned int)s << 7) | (unsigned int)(d & 127);
    }
}

// fused: per-bucket degree count -> in-bucket scan -> rowptr -> local scatter.
__global__ __launch_bounds__(256) void node_scan_scatter(
    const unsigned int* __restrict__ bucketPacked, const int* __restrict__ bucketBase,
    int* __restrict__ rowptr, int* __restrict__ csr_src) {
    __shared__ int cnt[128];
    __shared__ int half0;
    __shared__ unsigned int stage[CAP];
    int tid = threadIdx.x;
    if (tid < 128) cnt[tid] = 0;
    __syncthreads();
    int beg = bucketBase[blockIdx.x], end = bucketBase[blockIdx.x + 1];
    int n = end - beg;
    for (int i = tid; i < n; i += 256) {
        unsigned int e = bucketPacked[beg + i];
        if (i < CAP) stage[i] = e;
        atomicAdd(&cnt[e & 127], 1);
    }
    __syncthreads();
    int lane = tid & 63;
    int v    = (tid < 128) ? cnt[tid] : 0;
    int incl = v;
#pragma unroll
    for (int off = 1; off < 64; off <<= 1) {
        int t = __shfl_up(incl, off, 64);
        if (lane >= off) incl += t;
    }
    if (tid == 63) half0 = incl;
    __syncthreads();
    int base  = beg + ((tid >= 64 && tid < 128) ? half0 : 0);
    int start = base + incl - v;
    int node  = blockIdx.x * 128 + tid;
    if (tid < 128) {
        if (node < N_NODES) rowptr[node] = start;
        cnt[tid] = start;   // becomes the scatter cursor
    }
    if (blockIdx.x == 0 && tid == 128) rowptr[N_NODES] = N_EDGES;
    __syncthreads();
    for (int i = tid; i < n; i += 256) {
        unsigned int e = (i < CAP) ? stage[i] : bucketPacked[beg + i];
        int pos = atomicAdd(&cnt[e & 127], 1);
        csr_src[pos] = (int)(e >> 7);
    }
}

// ==== compute kernels ========================================================

// pack W[K x 64] fp32 -> bf16 MFMA B-fragment order (one slot per thread)
template <int K>
__device__ __forceinline__ void pack_body(const float* __restrict__ wS,
                                          const float* __restrict__ wN,
                                          unsigned short* __restrict__ pS,
                                          unsigned short* __restrict__ pN, int blk) {
    constexpr int NSLOT = (K / 32) * 4 * 64;
    int slot = blk * 256 + (int)threadIdx.x;
    if (slot >= NSLOT) return;
    int lane = slot & 63;
    int ct   = slot >> 6;
    int t    = ct & 3;
    int c    = ct >> 2;
    int m    = lane & 15;
    int quad = lane >> 4;
    int col  = t * 16 + m;
#pragma unroll
    for (int j = 0; j < 8; ++j) {
        int k = c * 32 + quad * 8 + j;
        pS[slot * 8 + j] = f2bf(wS[k * 64 + col]);
        pN[slot * 8 + j] = f2bf(wN[k * 64 + col]);
    }
}

// all three layers' weights in one dispatch: blocks 0-3 = L0, 4-5 = L1, 6-7 = L2
__global__ __launch_bounds__(256) void pack_all(
    const float* __restrict__ w0s, const float* __restrict__ w0n,
    const float* __restrict__ w1s, const float* __restrict__ w1n,
    const float* __restrict__ w2s, const float* __restrict__ w2n,
    unsigned short* __restrict__ p0S, unsigned short* __restrict__ p0N,
    unsigned short* __restrict__ p1S, unsigned short* __restrict__ p1N,
    unsigned short* __restrict__ p2S, unsigned short* __restrict__ p2N) {
    int blk = blockIdx.x;
    if (blk < 4)      pack_body<IN_DIM>(w0s, w0n, p0S, p0N, blk);
    else if (blk < 6) pack_body<HID>(w1s, w1n, p1S, p1N, blk - 4);
    else              pack_body<HID>(w2s, w2n, p2S, p2N, blk - 6);
}

// dual GEMM via MFMA: hs = A@wS (fp32 out), hn = A@wN (bf16 out).
// F32IN: A is fp32 (layer 0) — convert fragments in registers, no staging pass.
template <int K, bool F32IN>
__global__ __launch_bounds__(256) void gemm_dual_mfma(
    const void* __restrict__ Av,
    const unsigned short* __restrict__ pS,
    const unsigned short* __restrict__ pN,
    float* __restrict__ hs, unsigned short* __restrict__ hnb) {
    constexpr int NC = K / 32;
    int lane = threadIdx.x & 63;
    int wv   = threadIdx.x >> 6;
    int tile = blockIdx.x * 4 + wv;
    if (tile >= N_NODES / 16) return;
    int m    = lane & 15;
    int quad = lane >> 4;

    const short8* pSf = (const short8*)pS;
    const short8* pNf = (const short8*)pN;

    f32x4 accS[4], accN[4];
#pragma unroll
    for (int t = 0; t < 4; ++t) {
        accS[t] = (f32x4){0.f, 0.f, 0.f, 0.f};
        accN[t] = (f32x4){0.f, 0.f, 0.f, 0.f};
    }
#pragma unroll
    for (int c = 0; c < NC; ++c) {
        short8 a;
        if constexpr (F32IN) {
            const float* Af = (const float*)Av + ((size_t)tile * 16 + m) * K + quad * 8 + c * 32;
            f32x4 a0 = *(const f32x4*)Af;
            f32x4 a1 = *(const f32x4*)(Af + 4);
#pragma unroll
            for (int k = 0; k < 4; ++k) a[k]     = (short)f2bf(a0[k]);
#pragma unroll
            for (int k = 0; k < 4; ++k) a[k + 4] = (short)f2bf(a1[k]);
        } else {
            const short8* Af = (const short8*)((const unsigned short*)Av +
                               ((size_t)tile * 16 + m) * K + quad * 8);
            a = Af[c * 4];
        }
#pragma unroll
        for (int t = 0; t < 4; ++t) {
            short8 bs = pSf[(c * 4 + t) * 64 + lane];
            short8 bn = pNf[(c * 4 + t) * 64 + lane];
            accS[t] = __builtin_amdgcn_mfma_f32_16x16x32_bf16(a, bs, accS[t], 0, 0, 0);
            accN[t] = __builtin_amdgcn_mfma_f32_16x16x32_bf16(a, bn, accN[t], 0, 0, 0);
        }
    }
    int row0 = tile * 16 + quad * 4;
#pragma unroll
    for (int t = 0; t < 4; ++t) {
#pragma unroll
        for (int r = 0; r < 4; ++r) {
            size_t o = (size_t)(row0 + r) * HID + t * 16 + m;
            hs[o]  = accS[t][r];
            hnb[o] = f2bf(accN[t][r]);
        }
    }
}

// fused gather-aggregate + update. Lane = (g,r): g = edge slot (8 edges in
// flight), r = 16B chunk of the 128B bf16 row.
__global__ __launch_bounds__(256) void agg_update(
    const int* __restrict__ rowptr, const int* __restrict__ csr_src,
    const unsigned short* __restrict__ hnb, const float* __restrict__ hs,
    unsigned short* __restrict__ hb_out) {
    int node = (blockIdx.x * 256 + threadIdx.x) >> 6;
    int lane = threadIdx.x & 63;
    if (node >= N_NODES) return;
    int g = lane >> 3;   // edge slot 0..7
    int r = lane & 7;    // 16B chunk 0..7
    int beg = rowptr[node];
    int end = rowptr[node + 1];
    float acc[8] = {0.f, 0.f, 0.f, 0.f, 0.f, 0.f, 0.f, 0.f};
    for (int e = beg; e < end; e += 64) {
        int cnt = min(64, end - e);
        int idx = (lane < cnt) ? csr_src[e + lane] : 0;
        for (int j = 0; j < cnt; j += 8) {
            int s = __shfl(idx, j + g, 64);
            if (j + g < cnt) {
                uint4 w = *(const uint4*)(hnb + (size_t)s * HID + r * 8);
                acc[0] += bf2f(w.x << 16);  acc[1] += bf2f(w.x & 0xffff0000u);
                acc[2] += bf2f(w.y << 16);  acc[3] += bf2f(w.y & 0xffff0000u);
                acc[4] += bf2f(w.z << 16);  acc[5] += bf2f(w.z & 0xffff0000u);
                acc[6] += bf2f(w.w << 16);  acc[7] += bf2f(w.w & 0xffff0000u);
            }
        }
    }
#pragma unroll
    for (int k = 0; k < 8; ++k) {
        acc[k] += __shfl_xor(acc[k], 8, 64);
        acc[k] += __shfl_xor(acc[k], 16, 64);
        acc[k] += __shfl_xor(acc[k], 32, 64);
    }
    float invdeg = 1.0f / fmaxf((float)(end - beg), 1.0f);
    const float* hsr = hs + (size_t)node * HID + r * 8;
    f32x4 h0 = *(const f32x4*)hsr;
    f32x4 h1 = *(const f32x4*)(hsr + 4);
    float v[8], ss = 0.f;
#pragma unroll
    for (int k = 0; k < 8; ++k) {
        float hk = (k < 4) ? h0[k] : h1[k - 4];
        v[k] = fmaxf(fmaf(acc[k], invdeg, hk), 0.f);
        ss += v[k] * v[k];
    }
    ss += __shfl_xor(ss, 1, 64);
    ss += __shfl_xor(ss, 2, 64);
    ss += __shfl_xor(ss, 4, 64);
    float rs = 1.0f / (sqrtf(ss) + EPS);
    if (lane < 8) {   // g==0 lanes write: 8 lanes x 16B = full 128B row
        ushort8 o;
#pragma unroll
        for (int k = 0; k < 8; ++k) o[k] = f2bf(v[k] * rs);
        *(ushort8*)(hb_out + (size_t)node * HID + r * 8) = o;
    }
}

// MLP head
__global__ __launch_bounds__(256) void mlp_kernel(
    const unsigned short* __restrict__ hb, const float* __restrict__ mw1,
    const float* __restrict__ mb1, const float* __restrict__ mw2,
    const float* __restrict__ mb2, float* __restrict__ out) {
    __shared__ float sW1[HID * 32];
    __shared__ float sW2[32];
    for (int i = threadIdx.x; i < HID * 32; i += 256) sW1[i] = mw1[i];
    if (threadIdx.x < 32) sW2[threadIdx.x] = mw2[threadIdx.x];
    __syncthreads();
    int gid  = blockIdx.x * 256 + threadIdx.x;
    int node = gid >> 6;
    int lane = threadIdx.x & 63;
    if (node >= N_NODES) return;
    const unsigned short* hr = hb + (size_t)node * HID;
    float p = 0.f;
    if (lane < 32) {
        float acc = mb1[lane];
#pragma unroll
        for (int k = 0; k < HID; ++k)
            acc = fmaf(bf2f(((unsigned int)hr[k]) << 16), sW1[k * 32 + lane], acc);
        p = fmaxf(acc, 0.f) * sW2[lane];
    }
    float s = p;
#pragma unroll
    for (int off = 32; off >= 1; off >>= 1) s += __shfl_xor(s, off, 64);
    if (lane == 0) out[node] = 1.0f / (1.0f + __expf(-(s + mb2[0])));
}

extern "C" void kernel_launch(void* const* d_in, const int* in_sizes, int n_in,
                              void* d_out, int out_size, void* d_ws, size_t ws_size,
                              hipStream_t stream) {
    const float* x   = (const float*)d_in[0];
    const int*   ei  = (const int*)d_in[1];
    const float* w0s = (const float*)d_in[2];
    const float* w0n = (const float*)d_in[3];
    const float* w1s = (const float*)d_in[4];
    const float* w1n = (const float*)d_in[5];
    const float* w2s = (const float*)d_in[6];
    const float* w2n = (const float*)d_in[7];
    const float* mw1 = (const float*)d_in[8];
    const float* mb1 = (const float*)d_in[9];
    const float* mw2 = (const float*)d_in[10];
    const float* mb2 = (const float*)d_in[11];
    float*       out = (float*)d_out;

    // ---- workspace layout ----
    int* rowptr      = (int*)d_ws;               // 50432 (>= N+1)
    int* csr_src     = rowptr + 50432;           // 1.6M
    int* blockCounts = csr_src + N_EDGES;        // NBLK*NB = 152881 (pad 153600)
    int* bucketBase  = blockCounts + 153600;     // 512
    int* totals      = bucketBase + 512;         // 512
    unsigned int* bucketPacked = (unsigned int*)(totals + 512);   // 1.6M uint (6.4MB)
    const size_t NH = (size_t)N_NODES * HID;
    float*          hs  = (float*)(bucketPacked + N_EDGES);
    unsigned short* hnb = (unsigned short*)(hs + NH);
    unsigned short* hb  = hnb + NH;
    unsigned short* p0S = hb + NH;               // 128*64
    unsigned short* p0N = p0S + IN_DIM * HID;
    unsigned short* p1S = p0N + IN_DIM * HID;    // 64*64
    unsigned short* p1N = p1S + HID * HID;
    unsigned short* p2S = p1N + HID * HID;
    unsigned short* p2N = p2S + HID * HID;
    // total ~40 MB

    const int nodeGrid = (N_NODES * HID) / 256;  // 12500
    const int gemmGrid = (N_NODES / 16 + 3) / 4; // 782

    // ---- CSR build (binned counting sort; fully parallel scan) ----
    bucket_count<<<NBLK, 256, 0, stream>>>(ei, blockCounts);
    col_sum<<<NB, 256, 0, stream>>>(blockCounts, totals);
    base_scan<<<1, 64, 0, stream>>>(totals, bucketBase);
    col_fix<<<NB, 256, 0, stream>>>(blockCounts, bucketBase);
    bucket_scatter<<<NBLK, 256, 0, stream>>>(ei, blockCounts, bucketPacked);
    node_scan_scatter<<<NB, 256, 0, stream>>>(bucketPacked, bucketBase, rowptr, csr_src);

    // ---- weight packing (single dispatch) ----
    pack_all<<<8, 256, 0, stream>>>(w0s, w0n, w1s, w1n, w2s, w2n,
                                    p0S, p0N, p1S, p1N, p2S, p2N);

    // ---- layer 0 (K = 128, fp32 input converted in-register) ----
    gemm_dual_mfma<IN_DIM, true><<<gemmGrid, 256, 0, stream>>>(x, p0S, p0N, hs, hnb);
    agg_update<<<nodeGrid, 256, 0, stream>>>(rowptr, csr_src, hnb, hs, hb);

    // ---- layer 1 ----
    gemm_dual_mfma<HID, false><<<gemmGrid, 256, 0, stream>>>(hb, p1S, p1N, hs, hnb);
    agg_update<<<nodeGrid, 256, 0, stream>>>(rowptr, csr_src, hnb, hs, hb);

    // ---- layer 2 ----
    gemm_dual_mfma<HID, false><<<gemmGrid, 256, 0, stream>>>(hb, p2S, p2N, hs, hnb);
    agg_update<<<nodeGrid, 256, 0, stream>>>(rowptr, csr_src, hnb, hs, hb);

    // ---- MLP head ----
    mlp_kernel<<<nodeGrid, 256, 0, stream>>>(hb, mw1, mb1, mw2, mb2, out);
}

// Round 8
// 286.816 us; speedup vs baseline: 5.1894x; 1.0287x over previous
//
#include <hip/hip_runtime.h>
#include <hip/hip_bf16.h>
#include <math.h>

#define N_NODES 50000
#define N_EDGES 1600000
#define IN_DIM  128
#define HID     64
#define EPB     4096   // edges per sort block
#define NBLK    391    // ceil(N_EDGES / EPB)
#define NB      391    // ceil(N_NODES / 128) buckets of 128 nodes
#define CAP     8192   // LDS staging capacity (edges/bucket; mean 4092)
static constexpr float EPS = 1e-6f;

typedef __attribute__((ext_vector_type(8))) short          short8;   // 8 bf16
typedef __attribute__((ext_vector_type(8))) unsigned short ushort8;
typedef __attribute__((ext_vector_type(4))) float          f32x4;

__device__ __forceinline__ float bf2f(unsigned int hi_bits) {   // bits already in [31:16]
    union { unsigned int i; float f; } c; c.i = hi_bits; return c.f;
}
__device__ __forceinline__ unsigned short f2bf(float f) {   // round-nearest-even
    union { float f; unsigned int i; } c; c.f = f;
    unsigned int r = c.i + 0x7FFFu + ((c.i >> 16) & 1u);
    return (unsigned short)(r >> 16);
}
__device__ __forceinline__ unsigned char f2fp8(float f) {   // OCP e4m3, HW cvt
    int p = __builtin_amdgcn_cvt_pk_fp8_f32(f, f, 0, false);
    return (unsigned char)(p & 0xff);
}

// ==== CSR build: binned counting sort (packed edges, no global atomics) ======

// pack W[K x 64] fp32 -> bf16 MFMA B-fragment order (one slot per thread)
template <int K>
__device__ __forceinline__ void pack_body(const float* __restrict__ wS,
                                          const float* __restrict__ wN,
                                          unsigned short* __restrict__ pS,
                                          unsigned short* __restrict__ pN, int blk) {
    constexpr int NSLOT = (K / 32) * 4 * 64;
    int slot = blk * 256 + (int)threadIdx.x;
    if (slot >= NSLOT) return;
    int lane = slot & 63;
    int ct   = slot >> 6;
    int t    = ct & 3;
    int c    = ct >> 2;
    int m    = lane & 15;
    int quad = lane >> 4;
    int col  = t * 16 + m;
#pragma unroll
    for (int j = 0; j < 8; ++j) {
        int k = c * 32 + quad * 8 + j;
        pS[slot * 8 + j] = f2bf(wS[k * 64 + col]);
        pN[slot * 8 + j] = f2bf(wN[k * 64 + col]);
    }
}

// blocks 0..NBLK-1: per-block bucket histogram; blocks NBLK..NBLK+7: weight pack
__global__ __launch_bounds__(256) void bucket_count_pack(
    const int* __restrict__ ei, int* __restrict__ blockCounts,
    const float* __restrict__ w0s, const float* __restrict__ w0n,
    const float* __restrict__ w1s, const float* __restrict__ w1n,
    const float* __restrict__ w2s, const float* __restrict__ w2n,
    unsigned short* __restrict__ p0S, unsigned short* __restrict__ p0N,
    unsigned short* __restrict__ p1S, unsigned short* __restrict__ p1N,
    unsigned short* __restrict__ p2S, unsigned short* __restrict__ p2N) {
    if (blockIdx.x >= NBLK) {
        int blk = blockIdx.x - NBLK;
        if (blk < 4)      pack_body<IN_DIM>(w0s, w0n, p0S, p0N, blk);
        else if (blk < 6) pack_body<HID>(w1s, w1n, p1S, p1N, blk - 4);
        else              pack_body<HID>(w2s, w2n, p2S, p2N, blk - 6);
        return;
    }
    __shared__ int hist[NB];
    for (int i = threadIdx.x; i < NB; i += 256) hist[i] = 0;
    __syncthreads();
    int base = blockIdx.x * EPB;
    int lim  = min(EPB, N_EDGES - base);
    for (int i = threadIdx.x; i < lim; i += 256)
        atomicAdd(&hist[ei[N_EDGES + base + i] >> 7], 1);
    __syncthreads();
    for (int b = threadIdx.x; b < NB; b += 256)
        blockCounts[blockIdx.x * NB + b] = hist[b];
}

// totals[b] = sum_i blockCounts[i][b]   (391 blocks, one column each)
__global__ __launch_bounds__(256) void col_sum(const int* __restrict__ blockCounts,
                                               int* __restrict__ totals) {
    __shared__ int ws[4];
    int b = blockIdx.x;
    int s = 0;
    for (int i = threadIdx.x; i < NBLK; i += 256) s += blockCounts[i * NB + b];
#pragma unroll
    for (int off = 32; off >= 1; off >>= 1) s += __shfl_xor(s, off, 64);
    if ((threadIdx.x & 63) == 0) ws[threadIdx.x >> 6] = s;
    __syncthreads();
    if (threadIdx.x == 0) totals[b] = ws[0] + ws[1] + ws[2] + ws[3];
}

// exclusive scan of totals[0..NB) -> bucketBase[0..NB]   (one wave)
__global__ __launch_bounds__(64) void base_scan(const int* __restrict__ totals,
                                                int* __restrict__ bucketBase) {
    int lane  = threadIdx.x;
    int carry = 0;
    for (int base = 0; base < NB; base += 64) {
        int i = base + lane;
        int v = (i < NB) ? totals[i] : 0;
        int incl = v;
#pragma unroll
        for (int off = 1; off < 64; off <<= 1) {
            int t = __shfl_up(incl, off, 64);
            if (lane >= off) incl += t;
        }
        if (i < NB) bucketBase[i] = carry + incl - v;
        carry += __shfl(incl, 63, 64);
    }
    if (lane == 0) bucketBase[NB] = carry;   // == N_EDGES
}

// blockCounts[i][b] = bucketBase[b] + excl-prefix_i of column b  (391 blocks)
__global__ __launch_bounds__(256) void col_fix(int* __restrict__ blockCounts,
                                               const int* __restrict__ bucketBase) {
    __shared__ int vals[NBLK];
    int b = blockIdx.x;
    for (int i = threadIdx.x; i < NBLK; i += 256) vals[i] = blockCounts[i * NB + b];
    __syncthreads();
    if (threadIdx.x < 64) {
        int lane  = threadIdx.x;
        int carry = bucketBase[b];
        for (int base = 0; base < NBLK; base += 64) {
            int i = base + lane;
            int v = (i < NBLK) ? vals[i] : 0;
            int incl = v;
#pragma unroll
            for (int off = 1; off < 64; off <<= 1) {
                int t = __shfl_up(incl, off, 64);
                if (lane >= off) incl += t;
            }
            if (i < NBLK) vals[i] = carry + incl - v;
            carry += __shfl(incl, 63, 64);
        }
    }
    __syncthreads();
    for (int i = threadIdx.x; i < NBLK; i += 256) blockCounts[i * NB + b] = vals[i];
}

// scatter edges into bucket-sorted order, packed (src<<7)|(dst&127)
__global__ __launch_bounds__(256) void bucket_scatter(const int* __restrict__ ei,
                                                      const int* __restrict__ blockCounts,
                                                      unsigned int* __restrict__ bucketPacked) {
    __shared__ int cur[NB];
    for (int b = threadIdx.x; b < NB; b += 256)
        cur[b] = blockCounts[blockIdx.x * NB + b];
    __syncthreads();
    int base = blockIdx.x * EPB;
    int lim  = min(EPB, N_EDGES - base);
    for (int i = threadIdx.x; i < lim; i += 256) {
        int s = ei[base + i];
        int d = ei[N_EDGES + base + i];
        int pos = atomicAdd(&cur[d >> 7], 1);
        bucketPacked[pos] = ((unsigned int)s << 7) | (unsigned int)(d & 127);
    }
}

// fused: per-bucket degree count -> in-bucket scan -> rowptr -> local scatter.
__global__ __launch_bounds__(256) void node_scan_scatter(
    const unsigned int* __restrict__ bucketPacked, const int* __restrict__ bucketBase,
    int* __restrict__ rowptr, int* __restrict__ csr_src) {
    __shared__ int cnt[128];
    __shared__ int half0;
    __shared__ unsigned int stage[CAP];
    int tid = threadIdx.x;
    if (tid < 128) cnt[tid] = 0;
    __syncthreads();
    int beg = bucketBase[blockIdx.x], end = bucketBase[blockIdx.x + 1];
    int n = end - beg;
    for (int i = tid; i < n; i += 256) {
        unsigned int e = bucketPacked[beg + i];
        if (i < CAP) stage[i] = e;
        atomicAdd(&cnt[e & 127], 1);
    }
    __syncthreads();
    int lane = tid & 63;
    int v    = (tid < 128) ? cnt[tid] : 0;
    int incl = v;
#pragma unroll
    for (int off = 1; off < 64; off <<= 1) {
        int t = __shfl_up(incl, off, 64);
        if (lane >= off) incl += t;
    }
    if (tid == 63) half0 = incl;
    __syncthreads();
    int base  = beg + ((tid >= 64 && tid < 128) ? half0 : 0);
    int start = base + incl - v;
    int node  = blockIdx.x * 128 + tid;
    if (tid < 128) {
        if (node < N_NODES) rowptr[node] = start;
        cnt[tid] = start;   // becomes the scatter cursor
    }
    if (blockIdx.x == 0 && tid == 128) rowptr[N_NODES] = N_EDGES;
    __syncthreads();
    for (int i = tid; i < n; i += 256) {
        unsigned int e = (i < CAP) ? stage[i] : bucketPacked[beg + i];
        int pos = atomicAdd(&cnt[e & 127], 1);
        csr_src[pos] = (int)(e >> 7);
    }
}

// ==== compute kernels ========================================================

// dual GEMM via MFMA: hs = A@wS (fp32 out), hn = A@wN (fp8 e4m3 out).
// F32IN: A is fp32 (layer 0) — convert fragments in registers, no staging pass.
template <int K, bool F32IN>
__global__ __launch_bounds__(256) void gemm_dual_mfma(
    const void* __restrict__ Av,
    const unsigned short* __restrict__ pS,
    const unsigned short* __restrict__ pN,
    float* __restrict__ hs, unsigned char* __restrict__ hnq) {
    constexpr int NC = K / 32;
    int lane = threadIdx.x & 63;
    int wv   = threadIdx.x >> 6;
    int tile = blockIdx.x * 4 + wv;
    if (tile >= N_NODES / 16) return;
    int m    = lane & 15;
    int quad = lane >> 4;

    const short8* pSf = (const short8*)pS;
    const short8* pNf = (const short8*)pN;

    f32x4 accS[4], accN[4];
#pragma unroll
    for (int t = 0; t < 4; ++t) {
        accS[t] = (f32x4){0.f, 0.f, 0.f, 0.f};
        accN[t] = (f32x4){0.f, 0.f, 0.f, 0.f};
    }
#pragma unroll
    for (int c = 0; c < NC; ++c) {
        short8 a;
        if constexpr (F32IN) {
            const float* Af = (const float*)Av + ((size_t)tile * 16 + m) * K + quad * 8 + c * 32;
            f32x4 a0 = *(const f32x4*)Af;
            f32x4 a1 = *(const f32x4*)(Af + 4);
#pragma unroll
            for (int k = 0; k < 4; ++k) a[k]     = (short)f2bf(a0[k]);
#pragma unroll
            for (int k = 0; k < 4; ++k) a[k + 4] = (short)f2bf(a1[k]);
        } else {
            const short8* Af = (const short8*)((const unsigned short*)Av +
                               ((size_t)tile * 16 + m) * K + quad * 8);
            a = Af[c * 4];
        }
#pragma unroll
        for (int t = 0; t < 4; ++t) {
            short8 bs = pSf[(c * 4 + t) * 64 + lane];
            short8 bn = pNf[(c * 4 + t) * 64 + lane];
            accS[t] = __builtin_amdgcn_mfma_f32_16x16x32_bf16(a, bs, accS[t], 0, 0, 0);
            accN[t] = __builtin_amdgcn_mfma_f32_16x16x32_bf16(a, bn, accN[t], 0, 0, 0);
        }
    }
    int row0 = tile * 16 + quad * 4;
#pragma unroll
    for (int t = 0; t < 4; ++t) {
#pragma unroll
        for (int r = 0; r < 4; ++r) {
            size_t o = (size_t)(row0 + r) * HID + t * 16 + m;
            hs[o]  = accS[t][r];
            hnq[o] = f2fp8(accN[t][r]);
        }
    }
}

// fused gather-aggregate + update. Lane = (g,r): g = edge slot (8 edges in
// flight), r = 8B chunk of the 64B fp8 row. Rows are 64B -> half the cache
// line requests vs bf16.
__global__ __launch_bounds__(256) void agg_update(
    const int* __restrict__ rowptr, const int* __restrict__ csr_src,
    const unsigned char* __restrict__ hnq, const float* __restrict__ hs,
    unsigned short* __restrict__ hb_out) {
    int node = (blockIdx.x * 256 + threadIdx.x) >> 6;
    int lane = threadIdx.x & 63;
    if (node >= N_NODES) return;
    int g = lane >> 3;   // edge slot 0..7
    int r = lane & 7;    // 8B chunk 0..7
    int beg = rowptr[node];
    int end = rowptr[node + 1];
    float acc[8] = {0.f, 0.f, 0.f, 0.f, 0.f, 0.f, 0.f, 0.f};
    for (int e = beg; e < end; e += 64) {
        int cnt = min(64, end - e);
        int idx = (lane < cnt) ? csr_src[e + lane] : 0;
        for (int j = 0; j < cnt; j += 8) {
            int s = __shfl(idx, j + g, 64);
            if (j + g < cnt) {
                uint2 w = *(const uint2*)(hnq + (size_t)s * HID + r * 8);
                acc[0] += __builtin_amdgcn_cvt_f32_fp8((int)w.x, 0);
                acc[1] += __builtin_amdgcn_cvt_f32_fp8((int)w.x, 1);
                acc[2] += __builtin_amdgcn_cvt_f32_fp8((int)w.x, 2);
                acc[3] += __builtin_amdgcn_cvt_f32_fp8((int)w.x, 3);
                acc[4] += __builtin_amdgcn_cvt_f32_fp8((int)w.y, 0);
                acc[5] += __builtin_amdgcn_cvt_f32_fp8((int)w.y, 1);
                acc[6] += __builtin_amdgcn_cvt_f32_fp8((int)w.y, 2);
                acc[7] += __builtin_amdgcn_cvt_f32_fp8((int)w.y, 3);
            }
        }
    }
#pragma unroll
    for (int k = 0; k < 8; ++k) {
        acc[k] += __shfl_xor(acc[k], 8, 64);
        acc[k] += __shfl_xor(acc[k], 16, 64);
        acc[k] += __shfl_xor(acc[k], 32, 64);
    }
    float invdeg = 1.0f / fmaxf((float)(end - beg), 1.0f);
    const float* hsr = hs + (size_t)node * HID + r * 8;
    f32x4 h0 = *(const f32x4*)hsr;
    f32x4 h1 = *(const f32x4*)(hsr + 4);
    float v[8], ss = 0.f;
#pragma unroll
    for (int k = 0; k < 8; ++k) {
        float hk = (k < 4) ? h0[k] : h1[k - 4];
        v[k] = fmaxf(fmaf(acc[k], invdeg, hk), 0.f);
        ss += v[k] * v[k];
    }
    ss += __shfl_xor(ss, 1, 64);
    ss += __shfl_xor(ss, 2, 64);
    ss += __shfl_xor(ss, 4, 64);
    float rs = 1.0f / (sqrtf(ss) + EPS);
    if (lane < 8) {   // g==0 lanes write: 8 lanes x 16B = full 128B bf16 row
        ushort8 o;
#pragma unroll
        for (int k = 0; k < 8; ++k) o[k] = f2bf(v[k] * rs);
        *(ushort8*)(hb_out + (size_t)node * HID + r * 8) = o;
    }
}

// MLP head
__global__ __launch_bounds__(256) void mlp_kernel(
    const unsigned short* __restrict__ hb, const float* __restrict__ mw1,
    const float* __restrict__ mb1, const float* __restrict__ mw2,
    const float* __restrict__ mb2, float* __restrict__ out) {
    __shared__ float sW1[HID * 32];
    __shared__ float sW2[32];
    for (int i = threadIdx.x; i < HID * 32; i += 256) sW1[i] = mw1[i];
    if (threadIdx.x < 32) sW2[threadIdx.x] = mw2[threadIdx.x];
    __syncthreads();
    int gid  = blockIdx.x * 256 + threadIdx.x;
    int node = gid >> 6;
    int lane = threadIdx.x & 63;
    if (node >= N_NODES) return;
    const unsigned short* hr = hb + (size_t)node * HID;
    float p = 0.f;
    if (lane < 32) {
        float acc = mb1[lane];
#pragma unroll
        for (int k = 0; k < HID; ++k)
            acc = fmaf(bf2f(((unsigned int)hr[k]) << 16), sW1[k * 32 + lane], acc);
        p = fmaxf(acc, 0.f) * sW2[lane];
    }
    float s = p;
#pragma unroll
    for (int off = 32; off >= 1; off >>= 1) s += __shfl_xor(s, off, 64);
    if (lane == 0) out[node] = 1.0f / (1.0f + __expf(-(s + mb2[0])));
}

extern "C" void kernel_launch(void* const* d_in, const int* in_sizes, int n_in,
                              void* d_out, int out_size, void* d_ws, size_t ws_size,
                              hipStream_t stream) {
    const float* x   = (const float*)d_in[0];
    const int*   ei  = (const int*)d_in[1];
    const float* w0s = (const float*)d_in[2];
    const float* w0n = (const float*)d_in[3];
    const float* w1s = (const float*)d_in[4];
    const float* w1n = (const float*)d_in[5];
    const float* w2s = (const float*)d_in[6];
    const float* w2n = (const float*)d_in[7];
    const float* mw1 = (const float*)d_in[8];
    const float* mb1 = (const float*)d_in[9];
    const float* mw2 = (const float*)d_in[10];
    const float* mb2 = (const float*)d_in[11];
    float*       out = (float*)d_out;

    // ---- workspace layout (all sections 16B aligned) ----
    int* rowptr      = (int*)d_ws;               // 50432 (>= N+1)
    int* csr_src     = rowptr + 50432;           // 1.6M
    int* blockCounts = csr_src + N_EDGES;        // NBLK*NB = 152881 (pad 153600)
    int* bucketBase  = blockCounts + 153600;     // 512
    int* totals      = bucketBase + 512;         // 512
    unsigned int* bucketPacked = (unsigned int*)(totals + 512);   // 1.6M uint (6.4MB)
    const size_t NH = (size_t)N_NODES * HID;
    float*          hs  = (float*)(bucketPacked + N_EDGES);       // NH f32
    unsigned char*  hnq = (unsigned char*)(hs + NH);              // NH fp8
    unsigned short* hb  = (unsigned short*)(hnq + NH);            // NH bf16
    unsigned short* p0S = hb + NH;               // 128*64
    unsigned short* p0N = p0S + IN_DIM * HID;
    unsigned short* p1S = p0N + IN_DIM * HID;    // 64*64
    unsigned short* p1N = p1S + HID * HID;
    unsigned short* p2S = p1N + HID * HID;
    unsigned short* p2N = p2S + HID * HID;
    // total ~36 MB

    const int nodeGrid = (N_NODES * HID) / 256;  // 12500
    const int gemmGrid = (N_NODES / 16 + 3) / 4; // 782

    // ---- CSR build (binned counting sort; fully parallel scan) + weight pack ----
    bucket_count_pack<<<NBLK + 8, 256, 0, stream>>>(
        ei, blockCounts, w0s, w0n, w1s, w1n, w2s, w2n,
        p0S, p0N, p1S, p1N, p2S, p2N);
    col_sum<<<NB, 256, 0, stream>>>(blockCounts, totals);
    base_scan<<<1, 64, 0, stream>>>(totals, bucketBase);
    col_fix<<<NB, 256, 0, stream>>>(blockCounts, bucketBase);
    bucket_scatter<<<NBLK, 256, 0, stream>>>(ei, blockCounts, bucketPacked);
    node_scan_scatter<<<NB, 256, 0, stream>>>(bucketPacked, bucketBase, rowptr, csr_src);

    // ---- layer 0 (K = 128, fp32 input converted in-register) ----
    gemm_dual_mfma<IN_DIM, true><<<gemmGrid, 256, 0, stream>>>(x, p0S, p0N, hs, hnq);
    agg_update<<<nodeGrid, 256, 0, stream>>>(rowptr, csr_src, hnq, hs, hb);

    // ---- layer 1 ----
    gemm_dual_mfma<HID, false><<<gemmGrid, 256, 0, stream>>>(hb, p1S, p1N, hs, hnq);
    agg_update<<<nodeGrid, 256, 0, stream>>>(rowptr, csr_src, hnq, hs, hb);

    // ---- layer 2 ----
    gemm_dual_mfma<HID, false><<<gemmGrid, 256, 0, stream>>>(hb, p2S, p2N, hs, hnq);
    agg_update<<<nodeGrid, 256, 0, stream>>>(rowptr, csr_src, hnq, hs, hb);

    // ---- MLP head ----
    mlp_kernel<<<nodeGrid, 256, 0, stream>>>(hb, mw1, mb1, mw2, mb2, out);
}